// Round 7
// baseline (332.471 us; speedup 1.0000x reference)
//
#include <hip/hip_runtime.h>
#include <hip/hip_bf16.h>
#include <math.h>

#define NN 24576
#define NE 98304
#define ETOT (NE + NN)
#define NG 512
#define NB 512
#define LL 1000
#define TL 60
#define NTILE 17
#define PROT_BLKS (NB * NTILE)
#define CNT_BLKS (ETOT / 256)
#define AS1_BLKS (NN * 2 / 256)

typedef __attribute__((ext_vector_type(8))) short short8;
typedef __attribute__((ext_vector_type(4))) short short4v;
typedef __attribute__((ext_vector_type(4))) float f32x4;

__device__ inline short f2bf(float x) {
    union { __hip_bfloat16 b; short s; } u;
    u.b = __float2bfloat16(x);
    return u.s;
}

__device__ inline float bf2f(short s) {
    return __uint_as_float(((unsigned)(unsigned short)s) << 16);
}

// ---------------- D1: init + weight prep (disjoint block ranges) ----------------
__global__ void k_init_prep(int* deg, int* cursor, float* sums, int* ctr,
                            const float* K1, const float* K2, const float* W2, const float* Pe,
                            const float* W1, const float* as1c, const float* ad1c,
                            const float* as2c, const float* ad2c,
                            short* Bswz2, short* Bh2, short* Bl2, float* M1,
                            float* wvec) {
    int bid = blockIdx.x, t = threadIdx.x;
    if (bid < 256) {                       // init body
        int i = bid * 256 + t;
        if (i < NN) { deg[i] = 0; cursor[i] = 0; }
        if (i < NG * 128) sums[i] = 0.f;
        if (i < 2) ctr[i] = 0;
        return;
    }
    int idx = (bid - 256) * 256 + t;       // prep body (160 blocks)
    if (idx < 20) {             // was1 [0..9], wad1 [10..19]
        int q = idx % 10, hd = q / 5, f = q % 5;
        const float* av = (idx < 10) ? as1c : ad1c;
        float s = 0.f;
        for (int c = 0; c < 64; c++) s += W1[f * 128 + hd * 64 + c] * av[hd * 64 + c];
        wvec[idx < 10 ? q : 10 + q] = s;
    }
    if (idx >= 32 && idx < 288) {   // wa_s2 [32..159], wa_d2 [160..287]
        int q = idx - 32;
        int kk = q & 127;
        const float* av = (q < 128) ? as2c : ad2c;
        float s = 0.f;
        for (int n2 = 0; n2 < 128; n2++) s += W2[kk * 128 + n2] * av[n2];
        wvec[idx] = s;
    }
    if (idx < 22 * 3 * 64) {    // M1 table: M1[tok*192 + k*64 + oc] = sum_ic K1[oc][ic][k]*Pe[tok][ic]
        int tok = idx / 192, r2 = idx % 192;
        int k = r2 >> 6, oc = r2 & 63;
        float s = 0.f;
        for (int ic = 0; ic < 64; ic++) s += K1[oc * 192 + ic * 3 + k] * Pe[tok * 64 + ic];
        M1[idx] = s;
    }
    if (idx < 320 * 128) {      // B2
        int j = idx & 7, lane = (idx >> 3) & 63, rest = idx >> 9;
        int nt = rest & 7, kb = rest >> 3;
        int k = kb * 32 + ((lane >> 4) << 3) + j;
        int n = nt * 16 + (lane & 15);
        int kk = k / 64, i = k % 64;
        Bswz2[idx] = f2bf(K2[n * 320 + i * 5 + kk]);
    }
    if (idx < 128 * 128) {      // W2 hi/lo
        int j = idx & 7, lane = (idx >> 3) & 63, rest = idx >> 9;
        int nt = rest & 7, kb = rest >> 3;
        int k = kb * 32 + ((lane >> 4) << 3) + j;
        int n = nt * 16 + (lane & 15);
        float v = W2[k * 128 + n];
        short hh = f2bf(v);
        Bh2[idx] = hh;
        Bl2[idx] = f2bf(v - bf2f(hh));
    }
}

// ---------------- D2: protein (table-conv1 + MFMA conv2) + CSR count + as1/rec (R2-exact) ----------------
#define SSTR 72
__global__ __launch_bounds__(256, 6) void k_prot_cnt_as1(
    const int* seq, const float* M1, const float* bk1,
    const short* Bswz2, float* pmaxp,
    const int* ei, int* deg,
    const float* x, const float* wvec, float* rec) {
    int bid = blockIdx.x;
    int t = threadIdx.x;

    if (bid >= PROT_BLKS) {
        int rb = bid - PROT_BLKS;
        if (rb < CNT_BLKS) {               // CSR count
            int e = rb * 256 + t;
            int d = (e < NE) ? ei[NE + e] : e - NE;
            atomicAdd(&deg[d], 1);
        } else {                           // as1 + packed per-node record
            int idx = (rb - CNT_BLKS) * 256 + t;   // NN*2
            int n = idx >> 1, hd = idx & 1;
            float xv[5];
            float s = 0.f, dv = 0.f;
#pragma unroll
            for (int f = 0; f < 5; f++) {
                xv[f] = x[n * 5 + f];
                s += xv[f] * wvec[hd * 5 + f];
                dv += xv[f] * wvec[10 + hd * 5 + f];
            }
            float* rr = &rec[n * 16];
            if (hd == 0) {
#pragma unroll
                for (int f = 0; f < 5; f++) rr[f] = xv[f];
                rr[5] = s; rr[7] = dv;
            } else {
                rr[6] = s; rr[8] = dv;
            }
        }
        return;
    }

    // ---- protein body: tile of TL=60 positions (R2-exact) ----
    __shared__ __align__(16) short s1[68 * SSTR];   // conv1 out rows 0..67 (64 computed + 4 zero)

    int b = bid / NTILE;
    int tile = bid - b * NTILE;
    int t0 = tile * TL;

    if (t < 36) {   // zero s1 rows 64..67 (4*72=288 shorts)
        *(short8*)&s1[64 * SSTR + t * 8] = (short8){0, 0, 0, 0, 0, 0, 0, 0};
    }

    // conv1 via token table: s1[q][c] = elu(bk1[c] + sum_k M1[seq(l-1+k)][k][c]), l = t0-2+q
    {
        int q = t >> 2, c0 = (t & 3) << 4;   // 64 rows x 4 col-blocks of 16
        int l = t0 - 2 + q;
        short tmp[16];
        if (l >= 0 && l < LL) {
            float v[16];
#pragma unroll
            for (int j = 0; j < 4; j++) {
                float4 bv = *(const float4*)&bk1[c0 + j * 4];
                v[j * 4 + 0] = bv.x; v[j * 4 + 1] = bv.y; v[j * 4 + 2] = bv.z; v[j * 4 + 3] = bv.w;
            }
#pragma unroll
            for (int k = 0; k < 3; k++) {
                int lp = l - 1 + k;
                if (lp >= 0 && lp < LL) {
                    int tok = seq[b * LL + lp];
                    const float4* mr = (const float4*)&M1[tok * 192 + k * 64 + c0];
#pragma unroll
                    for (int j = 0; j < 4; j++) {
                        float4 mv = mr[j];
                        v[j * 4 + 0] += mv.x; v[j * 4 + 1] += mv.y;
                        v[j * 4 + 2] += mv.z; v[j * 4 + 3] += mv.w;
                    }
                }
            }
#pragma unroll
            for (int j = 0; j < 16; j++) {
                float xv = v[j];
                xv = xv > 0.f ? xv : __expf(xv) - 1.f;
                tmp[j] = f2bf(xv);
            }
        } else {
#pragma unroll
            for (int j = 0; j < 16; j++) tmp[j] = 0;
        }
        *(short8*)&s1[q * SSTR + c0] = *(short8*)&tmp[0];
        *(short8*)&s1[q * SSTR + c0 + 8] = *(short8*)&tmp[8];
    }
    __syncthreads();

    // conv2 MFMA. M=64 (4 mt), N=128 (8 nt), K=320 (10 kb); wave wv owns nt = {2wv, 2wv+1}
    int wv = t >> 6, lane = t & 63;
    int ln15 = lane & 15, quad = lane >> 4;

    f32x4 acc2[4][2];
#pragma unroll
    for (int mi = 0; mi < 4; mi++)
#pragma unroll
        for (int ni = 0; ni < 2; ni++) acc2[mi][ni] = (f32x4){0.f, 0.f, 0.f, 0.f};
#pragma unroll 2
    for (int kb = 0; kb < 10; kb++) {
        int koff = kb * 32 + quad * 8;
        int kk = koff >> 6, i0 = koff & 63;
        short8 a[4], bb[2];
#pragma unroll
        for (int mi = 0; mi < 4; mi++)
            a[mi] = *(const short8*)&s1[(mi * 16 + ln15 + kk) * SSTR + i0];
#pragma unroll
        for (int ni = 0; ni < 2; ni++)
            bb[ni] = *(const short8*)&Bswz2[((kb * 8 + wv * 2 + ni) * 64 + lane) * 8];
#pragma unroll
        for (int mi = 0; mi < 4; mi++)
#pragma unroll
            for (int ni = 0; ni < 2; ni++)
                acc2[mi][ni] = __builtin_amdgcn_mfma_f32_16x16x32_bf16(a[mi], bb[ni], acc2[mi][ni], 0, 0, 0);
    }

    // epilogue: masked raw max, plain store per (b,tile,col) — reduced in k_tail
#pragma unroll
    for (int ni = 0; ni < 2; ni++) {
        int col = (wv * 2 + ni) * 16 + ln15;
        float mx = -1e30f;
#pragma unroll
        for (int mi = 0; mi < 4; mi++) {
#pragma unroll
            for (int r = 0; r < 4; r++) {
                int p = mi * 16 + quad * 4 + r;
                if (p < TL && t0 + p < LL) mx = fmaxf(mx, acc2[mi][ni][r]);
            }
        }
        mx = fmaxf(mx, __shfl_xor(mx, 16, 64));
        mx = fmaxf(mx, __shfl_xor(mx, 32, 64));
        if (quad == 0) pmaxp[(b * NTILE + tile) * 128 + col] = mx;
    }
}

// ---------------- D3: merged CSR scan + scatter (two-stage spin barrier; 576 blocks co-resident) ----------------
__global__ __launch_bounds__(256) void k_scan_scatter(
    const int* deg, int* rowptr, int* part, int* ctr,
    const int* ei, int* cursor, int* colidx) {
    int bid = blockIdx.x, t = threadIdx.x;

    if (bid < 96) {
        __shared__ int s[256];
        __shared__ int sp[96];
        int i = bid * 256 + t;
        int v = deg[i];
        s[t] = v;
        __syncthreads();
        for (int o = 1; o < 256; o <<= 1) {
            int x2 = (t >= o) ? s[t - o] : 0;
            __syncthreads();
            s[t] += x2;
            __syncthreads();
        }
        int excl = s[t] - v;
        if (t == 255) {
            part[bid] = s[t];
            __threadfence();
            atomicAdd(&ctr[0], 1);
        }
        if (t == 0) {
            while (__hip_atomic_load(&ctr[0], __ATOMIC_ACQUIRE, __HIP_MEMORY_SCOPE_AGENT) < 96) {}
        }
        __syncthreads();
        if (t < 96) sp[t] = __hip_atomic_load(&part[t], __ATOMIC_RELAXED, __HIP_MEMORY_SCOPE_AGENT);
        __syncthreads();
        int pref = 0;
        for (int i2 = 0; i2 < bid; i2++) pref += sp[i2];
        rowptr[i] = excl + pref;
        if (i == 0) rowptr[NN] = ETOT;
        __threadfence();             // flush this thread's rowptr write
        __syncthreads();             // all threads' writes flushed
        if (t == 0) atomicAdd(&ctr[1], 1);
        return;
    }

    // scatter body: issue ei loads first, then wait for rowptr
    int e = (bid - 96) * 256 + t;    // e < ETOT exactly
    int s, d;
    if (e < NE) { s = ei[e]; d = ei[NE + e]; }
    else { s = d = e - NE; }
    if (t == 0) {
        while (__hip_atomic_load(&ctr[1], __ATOMIC_ACQUIRE, __HIP_MEMORY_SCOPE_AGENT) < 96) {}
    }
    __syncthreads();
    int base = __hip_atomic_load(&rowptr[d], __ATOMIC_RELAXED, __HIP_MEMORY_SCOPE_AGENT);
    int pos = atomicAdd(&cursor[d], 1);
    colidx[base + pos] = s;
}

// ---------------- GAT layer 1: x-space aggregation + fused W1 (packed 64B node records) ----------------
__global__ void k_agg2x(const int* rowptr, const int* colidx, const float* rec,
                        const float* W1, const float* b1, const float* wvec,
                        unsigned int* g1b, float* as2, float* ad2) {
    __shared__ float sW[640];
    __shared__ float sb1[128];
    __shared__ float swa[256];
    int t = threadIdx.x;
    for (int i = t; i < 640; i += 256) sW[i] = W1[i];
    if (t < 128) { sb1[t] = b1[t]; swa[t] = wvec[32 + t]; swa[128 + t] = wvec[160 + t]; }
    __syncthreads();

    int d = blockIdx.x * 16 + (t >> 4);   // grid = NN/16
    int g = t & 15;
    int hd = (g < 5) ? 0 : 1;
    int f = (g < 5) ? g : g - 5;
    float adv = rec[d * 16 + 7 + hd];
    int p0 = rowptr[d], p1 = rowptr[d + 1];
    float den = 0.f, acc = 0.f;
    if (g < 10) {
        for (int pc = p0; pc < p1; pc += 4) {
            int sarr[4]; float ev[4], xv[4];
#pragma unroll
            for (int i = 0; i < 4; i++) {
                int pp = pc + i;
                sarr[i] = colidx[pp < p1 ? pp : p1 - 1];
            }
#pragma unroll
            for (int i = 0; i < 4; i++) {
                ev[i] = rec[sarr[i] * 16 + 5 + hd];
                xv[i] = rec[sarr[i] * 16 + f];
            }
#pragma unroll
            for (int i = 0; i < 4; i++) {
                if (pc + i < p1) {
                    float e = ev[i] + adv;
                    e = e >= 0.f ? e : 0.2f * e;
                    float w = __expf(e);
                    den += w;
                    acc += w * xv[i];
                }
            }
        }
    }
    float xn = acc / (den + 1e-16f);
    int gb = (t & 63) & ~15;
    int hcol = g >> 3;
    float xs[5];
#pragma unroll
    for (int f2 = 0; f2 < 5; f2++)
        xs[f2] = __shfl(xn, gb + hcol * 5 + f2, 64);
    float ps = 0.f, pd = 0.f;
    float g1v[8];
#pragma unroll
    for (int k = 0; k < 8; k++) {
        int col = g * 8 + k;
        float v = sb1[col];
#pragma unroll
        for (int f2 = 0; f2 < 5; f2++) v += xs[f2] * sW[f2 * 128 + col];
        v = v > 0.f ? v : __expf(v) - 1.f;
        g1v[k] = v;
        ps += v * swa[col];
        pd += v * swa[128 + col];
    }
    uint4 pk;
    pk.x = ((unsigned)(unsigned short)f2bf(g1v[1]) << 16) | (unsigned)(unsigned short)f2bf(g1v[0]);
    pk.y = ((unsigned)(unsigned short)f2bf(g1v[3]) << 16) | (unsigned)(unsigned short)f2bf(g1v[2]);
    pk.z = ((unsigned)(unsigned short)f2bf(g1v[5]) << 16) | (unsigned)(unsigned short)f2bf(g1v[4]);
    pk.w = ((unsigned)(unsigned short)f2bf(g1v[7]) << 16) | (unsigned)(unsigned short)f2bf(g1v[6]);
    *(uint4*)&g1b[d * 64 + g * 4] = pk;
#pragma unroll
    for (int msk = 1; msk < 16; msk <<= 1) {
        ps += __shfl_xor(ps, msk, 64);
        pd += __shfl_xor(pd, msk, 64);
    }
    if (g == 0) { as2[d] = ps; ad2[d] = pd; }
}

// ---------------- GAT layer 2 aggregation in g1-space (packed bf16; no max-shift) ----------------
__global__ void k_agg1y(const int* rowptr, const int* colidx, const unsigned int* hb,
                        const float* as_, const float* ad_, float* yacc) {
    int t = threadIdx.x;
    int d = blockIdx.x * 4 + (t >> 6);   // wave per node
    int c = t & 63;
    float adv = ad_[d];
    int p0 = rowptr[d], p1 = rowptr[d + 1];
    float den = 0.f, acc0 = 0.f, acc1 = 0.f;
    for (int pc = p0; pc < p1; pc += 4) {
        int sarr[4]; float ev[4]; unsigned int hv[4];
#pragma unroll
        for (int i = 0; i < 4; i++) {
            int pp = pc + i;
            sarr[i] = colidx[pp < p1 ? pp : p1 - 1];
        }
#pragma unroll
        for (int i = 0; i < 4; i++) {
            ev[i] = as_[sarr[i]];
            hv[i] = hb[sarr[i] * 64 + c];
        }
#pragma unroll
        for (int i = 0; i < 4; i++) {
            if (pc + i < p1) {
                float e = ev[i] + adv;
                e = e >= 0.f ? e : 0.2f * e;
                float w = __expf(e);
                den += w;
                acc0 += w * __uint_as_float(hv[i] << 16);
                acc1 += w * __uint_as_float(hv[i] & 0xFFFF0000u);
            }
        }
    }
    float inv = 1.f / (den + 1e-16f);
    ((float2*)yacc)[d * 64 + c] = (float2){acc0 * inv, acc1 * inv};
}

// ---------------- layer-2 matmul + fused mean-pool scatter: sums += elu(yacc @ W2 + b2) ----------------
#define ASTR 136
__global__ __launch_bounds__(256, 2) void k_g2mm(
    const float* yacc, const short* Bh, const short* Bl, const float* b2,
    const int* batch, float* sums) {
    __shared__ __align__(16) short Ah[64 * ASTR];
    __shared__ __align__(16) short Al[64 * ASTR];
    __shared__ int sb[64];
    int t = threadIdx.x;
    int m0 = blockIdx.x * 64;
    int wv = t >> 6, lane = t & 63;
    int ln15 = lane & 15, quad = lane >> 4;

    if (t < 64) sb[t] = batch[m0 + t];
    for (int i = t; i < 64 * 32; i += 256) {
        int row = i >> 5, c4 = (i & 31) * 4;
        float4 v = *(const float4*)&yacc[(m0 + row) * 128 + c4];
        short4v hi, lo;
        hi.x = f2bf(v.x); lo.x = f2bf(v.x - bf2f(hi.x));
        hi.y = f2bf(v.y); lo.y = f2bf(v.y - bf2f(hi.y));
        hi.z = f2bf(v.z); lo.z = f2bf(v.z - bf2f(hi.z));
        hi.w = f2bf(v.w); lo.w = f2bf(v.w - bf2f(hi.w));
        *(short4v*)&Ah[row * ASTR + c4] = hi;
        *(short4v*)&Al[row * ASTR + c4] = lo;
    }
    __syncthreads();

    f32x4 acc[8];
#pragma unroll
    for (int nt = 0; nt < 8; nt++) acc[nt] = (f32x4){0.f, 0.f, 0.f, 0.f};
    int arow = wv * 16 + ln15;
#pragma unroll
    for (int kb = 0; kb < 4; kb++) {
        int koff = kb * 32 + quad * 8;
        short8 a_hi = *(const short8*)&Ah[arow * ASTR + koff];
        short8 a_lo = *(const short8*)&Al[arow * ASTR + koff];
#pragma unroll
        for (int nt = 0; nt < 8; nt++) {
            short8 bh = *(const short8*)&Bh[((kb * 8 + nt) * 64 + lane) * 8];
            short8 bl = *(const short8*)&Bl[((kb * 8 + nt) * 64 + lane) * 8];
            acc[nt] = __builtin_amdgcn_mfma_f32_16x16x32_bf16(a_hi, bh, acc[nt], 0, 0, 0);
            acc[nt] = __builtin_amdgcn_mfma_f32_16x16x32_bf16(a_hi, bl, acc[nt], 0, 0, 0);
            acc[nt] = __builtin_amdgcn_mfma_f32_16x16x32_bf16(a_lo, bh, acc[nt], 0, 0, 0);
        }
    }
    // epilogue: bias+elu, then segmented (sorted-batch) atomic accumulate into sums
    int rbase = wv * 16 + quad * 4;
#pragma unroll
    for (int nt = 0; nt < 8; nt++) {
        int col = nt * 16 + ln15;
        float bias = b2[col];
        float run = 0.f;
        int cg = sb[rbase];
#pragma unroll
        for (int r = 0; r < 4; r++) {
            float v = acc[nt][r] + bias;
            v = v > 0.f ? v : __expf(v) - 1.f;
            int g = sb[rbase + r];
            if (g != cg) {
                atomicAdd(&sums[cg * 128 + col], run);
                run = 0.f; cg = g;
            }
            run += v;
        }
        atomicAdd(&sums[cg * 128 + col], run);
    }
}

// ---------------- tail: pmax tile-reduce + cnt via binary search + head MLP ----------------
__global__ __launch_bounds__(512) void k_tail(
    const float* pmaxp, const float* bk2, const float* Wp, const float* bp,
    const float* sums, const int* batch, const float* Wd, const float* bd,
    const float* Wf1, const float* bf1, const float* Wf2, const float* bf2,
    const float* Wo, const float* bo, float* out) {
    __shared__ float spm[128];
    __shared__ float in2[512];
    __shared__ float part1[512];
    __shared__ float hh[128];
    __shared__ float part2[512];
    __shared__ float h2s[64];
    __shared__ int sLo, sHi;
    int g = blockIdx.x, t = threadIdx.x;

    if (t < 128) {   // reduce 17 tiles -> bias+elu once (elu monotonic)
        float m = -1e30f;
#pragma unroll
        for (int tt = 0; tt < NTILE; tt++)
            m = fmaxf(m, pmaxp[(g * NTILE + tt) * 128 + t]);
        float v = m + bk2[t];
        spm[t] = v > 0.f ? v : __expf(v) - 1.f;
    } else if (t == 128 || t == 129) {
        // cnt[g] = lower_bound(batch, g+1) - lower_bound(batch, g)  (batch sorted)
        int target = g + (t - 128);
        int lo = 0, hi = NN;
        while (lo < hi) {
            int mid = (lo + hi) >> 1;
            if (batch[mid] < target) lo = mid + 1; else hi = mid;
        }
        if (t == 128) sLo = lo; else sHi = lo;
    }
    __syncthreads();

    if (t < 256) {
        float pacc = bp[t];
#pragma unroll 8
        for (int i = 0; i < 128; i++) pacc += spm[i] * Wp[i * 256 + t];
        in2[256 + t] = pacc > 0.f ? pacc : 0.f;
    } else {
        int o = t - 256;
        float c = (float)(sHi - sLo); c = c < 1.f ? 1.f : c;
        float inv = 1.f / c;
        float dacc = bd[o];
#pragma unroll 8
        for (int i = 0; i < 128; i++) dacc += sums[g * 128 + i] * inv * Wd[i * 256 + o];
        in2[o] = dacc > 0.f ? dacc : 0.f;
    }
    __syncthreads();

    {
        int o = t >> 2, ks = t & 3;
        float p = 0.f;
        int c0 = ks * 128;
#pragma unroll 8
        for (int cc = c0; cc < c0 + 128; cc++) p += in2[cc] * Wf1[cc * 128 + o];
        part1[t] = p;
    }
    __syncthreads();
    if (t < 128) {
        float a = bf1[t] + part1[t * 4] + part1[t * 4 + 1] + part1[t * 4 + 2] + part1[t * 4 + 3];
        hh[t] = a > 0.f ? a : 0.f;
    }
    __syncthreads();

    {
        int o = t >> 3, ks = t & 7;
        float p = 0.f;
        int c0 = ks * 16;
#pragma unroll
        for (int cc = c0; cc < c0 + 16; cc++) p += hh[cc] * Wf2[cc * 64 + o];
        part2[t] = p;
    }
    __syncthreads();
    if (t < 64) {
        float a = bf2[t];
#pragma unroll
        for (int k = 0; k < 8; k++) a += part2[t * 8 + k];
        h2s[t] = a > 0.f ? a : 0.f;
    }
    __syncthreads();

    if (t < 64) {
        float p = h2s[t] * Wo[t];
#pragma unroll
        for (int off = 32; off > 0; off >>= 1) p += __shfl_down(p, off, 64);
        if (t == 0) out[g] = p + bo[0];
    }
}

extern "C" void kernel_launch(void* const* d_in, const int* in_sizes, int n_in,
                              void* d_out, int out_size, void* d_ws, size_t ws_size,
                              hipStream_t stream) {
    (void)in_sizes; (void)n_in; (void)out_size; (void)ws_size;
    const float* x   = (const float*)d_in[0];
    const int* ei    = (const int*)d_in[1];
    const int* batch = (const int*)d_in[2];
    const int* seq   = (const int*)d_in[3];
    const float* W1  = (const float*)d_in[4];
    const float* a_s1 = (const float*)d_in[5];
    const float* a_d1 = (const float*)d_in[6];
    const float* b1  = (const float*)d_in[7];
    const float* W2  = (const float*)d_in[8];
    const float* a_s2 = (const float*)d_in[9];
    const float* a_d2 = (const float*)d_in[10];
    const float* b2  = (const float*)d_in[11];
    const float* Wd  = (const float*)d_in[12];
    const float* bd  = (const float*)d_in[13];
    const float* Pe  = (const float*)d_in[14];
    const float* K1  = (const float*)d_in[15];
    const float* bk1 = (const float*)d_in[16];
    const float* K2  = (const float*)d_in[17];
    const float* bk2 = (const float*)d_in[18];
    const float* Wp  = (const float*)d_in[19];
    const float* bp  = (const float*)d_in[20];
    const float* Wf1 = (const float*)d_in[21];
    const float* bf1 = (const float*)d_in[22];
    const float* Wf2 = (const float*)d_in[23];
    const float* bf2 = (const float*)d_in[24];
    const float* Wo  = (const float*)d_in[25];
    const float* bo  = (const float*)d_in[26];
    float* out = (float*)d_out;

    float* w = (float*)d_ws;
    float* g1bf = w; w += NN * 64;    // packed-bf16 uint[NN*64]
    float* yacc = w; w += NN * 128;
    float* as2  = w; w += NN;
    float* ad2  = w; w += NN;
    float* sums = w; w += NG * 128;
    float* pmaxp = w; w += NB * NTILE * 128;   // per-tile raw max
    float* rec  = w; w += NN * 16;             // packed {x[5], as1[2], ad1[2]} per node
    float* wvec = w; w += 512;
    short* Bswz2 = (short*)w; w += 320 * 128 / 2;
    short* Bh2  = (short*)w; w += 128 * 128 / 2;
    short* Bl2  = (short*)w; w += 128 * 128 / 2;
    float* M1   = w; w += 22 * 3 * 64;
    int* deg    = (int*)w; w += NN;
    int* cursor = (int*)w; w += NN;
    int* part   = (int*)w; w += 128;
    int* ctr    = (int*)w; w += 8;
    int* rowptr = (int*)w; w += NN + 8;
    int* colidx = (int*)w; w += ETOT;

    unsigned int* g1b = (unsigned int*)g1bf;

    // D1: init + weight prep
    hipLaunchKernelGGL(k_init_prep, dim3(256 + 160), dim3(256), 0, stream,
                       deg, cursor, sums, ctr,
                       K1, K2, W2, Pe, W1, a_s1, a_d1, a_s2, a_d2,
                       Bswz2, Bh2, Bl2, M1, wvec);

    // D2: protein + CSR count + as1/rec
    hipLaunchKernelGGL(k_prot_cnt_as1, dim3(PROT_BLKS + CNT_BLKS + AS1_BLKS), dim3(256), 0, stream,
                       seq, M1, bk1, Bswz2, pmaxp,
                       ei, deg, x, wvec, rec);

    // D3: merged CSR scan + scatter
    hipLaunchKernelGGL(k_scan_scatter, dim3(96 + CNT_BLKS), dim3(256), 0, stream,
                       deg, rowptr, part, ctr, ei, cursor, colidx);

    // D4: GAT layer 1 aggregation (rec-space) + fused W1
    hipLaunchKernelGGL(k_agg2x, dim3(NN / 16), dim3(256), 0, stream,
                       rowptr, colidx, rec, W1, b1, wvec, g1b, as2, ad2);

    // D5: GAT layer 2 aggregation
    hipLaunchKernelGGL(k_agg1y, dim3(NN / 4), dim3(256), 0, stream,
                       rowptr, colidx, g1b, as2, ad2, yacc);

    // D6: W2 matmul + fused mean-pool scatter
    hipLaunchKernelGGL(k_g2mm, dim3(NN / 64), dim3(256), 0, stream,
                       yacc, Bh2, Bl2, b2, batch, sums);

    // D7: tail (pmax tile-reduce + binary-search cnt)
    hipLaunchKernelGGL(k_tail, dim3(NG), dim3(512), 0, stream,
                       pmaxp, bk2, Wp, bp, sums, batch, Wd, bd, Wf1, bf1, Wf2, bf2, Wo, bo, out);
}

// Round 8
// 271.622 us; speedup vs baseline: 1.2240x; 1.2240x over previous
//
#include <hip/hip_runtime.h>
#include <hip/hip_bf16.h>
#include <math.h>

#define NN 24576
#define NE 98304
#define ETOT (NE + NN)
#define NG 512
#define NB 512
#define LL 1000
#define TL 60
#define NTILE 17
#define PROT_BLKS (NB * NTILE)
#define CNT_BLKS (ETOT / 256)
#define AS1_BLKS (NN * 2 / 256)

typedef __attribute__((ext_vector_type(8))) short short8;
typedef __attribute__((ext_vector_type(4))) short short4v;
typedef __attribute__((ext_vector_type(4))) float f32x4;

__device__ inline short f2bf(float x) {
    union { __hip_bfloat16 b; short s; } u;
    u.b = __float2bfloat16(x);
    return u.s;
}

__device__ inline float bf2f(short s) {
    return __uint_as_float(((unsigned)(unsigned short)s) << 16);
}

// ---------------- D1: init + weight prep (disjoint block ranges) ----------------
__global__ void k_init_prep(int* deg, int* cursor, float* sums, int* ctr,
                            const float* K1, const float* K2, const float* W2, const float* Pe,
                            const float* W1, const float* as1c, const float* ad1c,
                            const float* as2c, const float* ad2c,
                            short* Bswz2, short* Bh2, short* Bl2, float* M1,
                            float* wvec) {
    int bid = blockIdx.x, t = threadIdx.x;
    if (bid < 256) {                       // init body
        int i = bid * 256 + t;
        if (i < NN) { deg[i] = 0; cursor[i] = 0; }
        if (i < NG * 128) sums[i] = 0.f;
        if (i < 2) ctr[i] = 0;
        return;
    }
    int idx = (bid - 256) * 256 + t;       // prep body (160 blocks)
    if (idx < 20) {             // was1 [0..9], wad1 [10..19]
        int q = idx % 10, hd = q / 5, f = q % 5;
        const float* av = (idx < 10) ? as1c : ad1c;
        float s = 0.f;
        for (int c = 0; c < 64; c++) s += W1[f * 128 + hd * 64 + c] * av[hd * 64 + c];
        wvec[idx < 10 ? q : 10 + q] = s;
    }
    if (idx >= 32 && idx < 288) {   // wa_s2 [32..159], wa_d2 [160..287]
        int q = idx - 32;
        int kk = q & 127;
        const float* av = (q < 128) ? as2c : ad2c;
        float s = 0.f;
        for (int n2 = 0; n2 < 128; n2++) s += W2[kk * 128 + n2] * av[n2];
        wvec[idx] = s;
    }
    if (idx < 22 * 3 * 64) {    // M1 table: M1[tok*192 + k*64 + oc] = sum_ic K1[oc][ic][k]*Pe[tok][ic]
        int tok = idx / 192, r2 = idx % 192;
        int k = r2 >> 6, oc = r2 & 63;
        float s = 0.f;
        for (int ic = 0; ic < 64; ic++) s += K1[oc * 192 + ic * 3 + k] * Pe[tok * 64 + ic];
        M1[idx] = s;
    }
    if (idx < 320 * 128) {      // B2
        int j = idx & 7, lane = (idx >> 3) & 63, rest = idx >> 9;
        int nt = rest & 7, kb = rest >> 3;
        int k = kb * 32 + ((lane >> 4) << 3) + j;
        int n = nt * 16 + (lane & 15);
        int kk = k / 64, i = k % 64;
        Bswz2[idx] = f2bf(K2[n * 320 + i * 5 + kk]);
    }
    if (idx < 128 * 128) {      // W2 hi/lo
        int j = idx & 7, lane = (idx >> 3) & 63, rest = idx >> 9;
        int nt = rest & 7, kb = rest >> 3;
        int k = kb * 32 + ((lane >> 4) << 3) + j;
        int n = nt * 16 + (lane & 15);
        float v = W2[k * 128 + n];
        short hh = f2bf(v);
        Bh2[idx] = hh;
        Bl2[idx] = f2bf(v - bf2f(hh));
    }
}

// ---------------- D2: protein (table-conv1 + MFMA conv2) + CSR count + as1/rec (R2-exact) ----------------
#define SSTR 72
__global__ __launch_bounds__(256, 6) void k_prot_cnt_as1(
    const int* seq, const float* M1, const float* bk1,
    const short* Bswz2, float* pmaxp,
    const int* ei, int* deg,
    const float* x, const float* wvec, float* rec) {
    int bid = blockIdx.x;
    int t = threadIdx.x;

    if (bid >= PROT_BLKS) {
        int rb = bid - PROT_BLKS;
        if (rb < CNT_BLKS) {               // CSR count
            int e = rb * 256 + t;
            int d = (e < NE) ? ei[NE + e] : e - NE;
            atomicAdd(&deg[d], 1);
        } else {                           // as1 + packed per-node record
            int idx = (rb - CNT_BLKS) * 256 + t;   // NN*2
            int n = idx >> 1, hd = idx & 1;
            float xv[5];
            float s = 0.f, dv = 0.f;
#pragma unroll
            for (int f = 0; f < 5; f++) {
                xv[f] = x[n * 5 + f];
                s += xv[f] * wvec[hd * 5 + f];
                dv += xv[f] * wvec[10 + hd * 5 + f];
            }
            float* rr = &rec[n * 16];
            if (hd == 0) {
#pragma unroll
                for (int f = 0; f < 5; f++) rr[f] = xv[f];
                rr[5] = s; rr[7] = dv;
            } else {
                rr[6] = s; rr[8] = dv;
            }
        }
        return;
    }

    // ---- protein body: tile of TL=60 positions (R2-exact) ----
    __shared__ __align__(16) short s1[68 * SSTR];   // conv1 out rows 0..67 (64 computed + 4 zero)

    int b = bid / NTILE;
    int tile = bid - b * NTILE;
    int t0 = tile * TL;

    if (t < 36) {   // zero s1 rows 64..67 (4*72=288 shorts)
        *(short8*)&s1[64 * SSTR + t * 8] = (short8){0, 0, 0, 0, 0, 0, 0, 0};
    }

    // conv1 via token table: s1[q][c] = elu(bk1[c] + sum_k M1[seq(l-1+k)][k][c]), l = t0-2+q
    {
        int q = t >> 2, c0 = (t & 3) << 4;   // 64 rows x 4 col-blocks of 16
        int l = t0 - 2 + q;
        short tmp[16];
        if (l >= 0 && l < LL) {
            float v[16];
#pragma unroll
            for (int j = 0; j < 4; j++) {
                float4 bv = *(const float4*)&bk1[c0 + j * 4];
                v[j * 4 + 0] = bv.x; v[j * 4 + 1] = bv.y; v[j * 4 + 2] = bv.z; v[j * 4 + 3] = bv.w;
            }
#pragma unroll
            for (int k = 0; k < 3; k++) {
                int lp = l - 1 + k;
                if (lp >= 0 && lp < LL) {
                    int tok = seq[b * LL + lp];
                    const float4* mr = (const float4*)&M1[tok * 192 + k * 64 + c0];
#pragma unroll
                    for (int j = 0; j < 4; j++) {
                        float4 mv = mr[j];
                        v[j * 4 + 0] += mv.x; v[j * 4 + 1] += mv.y;
                        v[j * 4 + 2] += mv.z; v[j * 4 + 3] += mv.w;
                    }
                }
            }
#pragma unroll
            for (int j = 0; j < 16; j++) {
                float xv = v[j];
                xv = xv > 0.f ? xv : __expf(xv) - 1.f;
                tmp[j] = f2bf(xv);
            }
        } else {
#pragma unroll
            for (int j = 0; j < 16; j++) tmp[j] = 0;
        }
        *(short8*)&s1[q * SSTR + c0] = *(short8*)&tmp[0];
        *(short8*)&s1[q * SSTR + c0 + 8] = *(short8*)&tmp[8];
    }
    __syncthreads();

    // conv2 MFMA. M=64 (4 mt), N=128 (8 nt), K=320 (10 kb); wave wv owns nt = {2wv, 2wv+1}
    int wv = t >> 6, lane = t & 63;
    int ln15 = lane & 15, quad = lane >> 4;

    f32x4 acc2[4][2];
#pragma unroll
    for (int mi = 0; mi < 4; mi++)
#pragma unroll
        for (int ni = 0; ni < 2; ni++) acc2[mi][ni] = (f32x4){0.f, 0.f, 0.f, 0.f};
#pragma unroll 2
    for (int kb = 0; kb < 10; kb++) {
        int koff = kb * 32 + quad * 8;
        int kk = koff >> 6, i0 = koff & 63;
        short8 a[4], bb[2];
#pragma unroll
        for (int mi = 0; mi < 4; mi++)
            a[mi] = *(const short8*)&s1[(mi * 16 + ln15 + kk) * SSTR + i0];
#pragma unroll
        for (int ni = 0; ni < 2; ni++)
            bb[ni] = *(const short8*)&Bswz2[((kb * 8 + wv * 2 + ni) * 64 + lane) * 8];
#pragma unroll
        for (int mi = 0; mi < 4; mi++)
#pragma unroll
            for (int ni = 0; ni < 2; ni++)
                acc2[mi][ni] = __builtin_amdgcn_mfma_f32_16x16x32_bf16(a[mi], bb[ni], acc2[mi][ni], 0, 0, 0);
    }

    // epilogue: masked raw max, plain store per (b,tile,col) — reduced in k_tail
#pragma unroll
    for (int ni = 0; ni < 2; ni++) {
        int col = (wv * 2 + ni) * 16 + ln15;
        float mx = -1e30f;
#pragma unroll
        for (int mi = 0; mi < 4; mi++) {
#pragma unroll
            for (int r = 0; r < 4; r++) {
                int p = mi * 16 + quad * 4 + r;
                if (p < TL && t0 + p < LL) mx = fmaxf(mx, acc2[mi][ni][r]);
            }
        }
        mx = fmaxf(mx, __shfl_xor(mx, 16, 64));
        mx = fmaxf(mx, __shfl_xor(mx, 32, 64));
        if (quad == 0) pmaxp[(b * NTILE + tile) * 128 + col] = mx;
    }
}

// ---------------- D3: merged CSR scan (96 peer blocks, spin barrier; R6-proven) ----------------
__global__ void k_scan(const int* deg, int* rowptr, int* part, int* ctr) {
    __shared__ int s[256];
    __shared__ int sp[96];
    int b = blockIdx.x, t = threadIdx.x, i = b * 256 + t;
    int v = deg[i];
    s[t] = v;
    __syncthreads();
    for (int o = 1; o < 256; o <<= 1) {
        int x2 = (t >= o) ? s[t - o] : 0;
        __syncthreads();
        s[t] += x2;
        __syncthreads();
    }
    int excl = s[t] - v;
    if (t == 255) {
        part[b] = s[t];
        __threadfence();
        atomicAdd(ctr, 1);
    }
    if (t == 0) {
        while (__hip_atomic_load(ctr, __ATOMIC_ACQUIRE, __HIP_MEMORY_SCOPE_AGENT) < 96) {}
    }
    __syncthreads();
    if (t < 96) sp[t] = __hip_atomic_load(&part[t], __ATOMIC_RELAXED, __HIP_MEMORY_SCOPE_AGENT);
    __syncthreads();
    int pref = 0;
    for (int i2 = 0; i2 < b; i2++) pref += sp[i2];
    rowptr[i] = excl + pref;
    if (i == 0) rowptr[NN] = ETOT;
}

// ---------------- D4: scatter ----------------
__global__ void k_scatter(const int* ei, const int* rowptr, int* cursor, int* colidx) {
    int e = blockIdx.x * 256 + threadIdx.x;
    if (e >= ETOT) return;
    int s, d;
    if (e < NE) { s = ei[e]; d = ei[NE + e]; }
    else { s = d = e - NE; }
    int pos = atomicAdd(&cursor[d], 1);
    colidx[rowptr[d] + pos] = s;
}

// ---------------- GAT layer 1: x-space aggregation + fused W1 (packed 64B node records) ----------------
__global__ void k_agg2x(const int* rowptr, const int* colidx, const float* rec,
                        const float* W1, const float* b1, const float* wvec,
                        unsigned int* g1b, float* as2, float* ad2) {
    __shared__ float sW[640];
    __shared__ float sb1[128];
    __shared__ float swa[256];
    int t = threadIdx.x;
    for (int i = t; i < 640; i += 256) sW[i] = W1[i];
    if (t < 128) { sb1[t] = b1[t]; swa[t] = wvec[32 + t]; swa[128 + t] = wvec[160 + t]; }
    __syncthreads();

    int d = blockIdx.x * 16 + (t >> 4);   // grid = NN/16
    int g = t & 15;
    int hd = (g < 5) ? 0 : 1;
    int f = (g < 5) ? g : g - 5;
    float adv = rec[d * 16 + 7 + hd];
    int p0 = rowptr[d], p1 = rowptr[d + 1];
    float den = 0.f, acc = 0.f;
    if (g < 10) {
        for (int pc = p0; pc < p1; pc += 4) {
            int sarr[4]; float ev[4], xv[4];
#pragma unroll
            for (int i = 0; i < 4; i++) {
                int pp = pc + i;
                sarr[i] = colidx[pp < p1 ? pp : p1 - 1];
            }
#pragma unroll
            for (int i = 0; i < 4; i++) {
                ev[i] = rec[sarr[i] * 16 + 5 + hd];
                xv[i] = rec[sarr[i] * 16 + f];
            }
#pragma unroll
            for (int i = 0; i < 4; i++) {
                if (pc + i < p1) {
                    float e = ev[i] + adv;
                    e = e >= 0.f ? e : 0.2f * e;
                    float w = __expf(e);
                    den += w;
                    acc += w * xv[i];
                }
            }
        }
    }
    float xn = acc / (den + 1e-16f);
    int gb = (t & 63) & ~15;
    int hcol = g >> 3;
    float xs[5];
#pragma unroll
    for (int f2 = 0; f2 < 5; f2++)
        xs[f2] = __shfl(xn, gb + hcol * 5 + f2, 64);
    float ps = 0.f, pd = 0.f;
    float g1v[8];
#pragma unroll
    for (int k = 0; k < 8; k++) {
        int col = g * 8 + k;
        float v = sb1[col];
#pragma unroll
        for (int f2 = 0; f2 < 5; f2++) v += xs[f2] * sW[f2 * 128 + col];
        v = v > 0.f ? v : __expf(v) - 1.f;
        g1v[k] = v;
        ps += v * swa[col];
        pd += v * swa[128 + col];
    }
    uint4 pk;
    pk.x = ((unsigned)(unsigned short)f2bf(g1v[1]) << 16) | (unsigned)(unsigned short)f2bf(g1v[0]);
    pk.y = ((unsigned)(unsigned short)f2bf(g1v[3]) << 16) | (unsigned)(unsigned short)f2bf(g1v[2]);
    pk.z = ((unsigned)(unsigned short)f2bf(g1v[5]) << 16) | (unsigned)(unsigned short)f2bf(g1v[4]);
    pk.w = ((unsigned)(unsigned short)f2bf(g1v[7]) << 16) | (unsigned)(unsigned short)f2bf(g1v[6]);
    *(uint4*)&g1b[d * 64 + g * 4] = pk;
#pragma unroll
    for (int msk = 1; msk < 16; msk <<= 1) {
        ps += __shfl_xor(ps, msk, 64);
        pd += __shfl_xor(pd, msk, 64);
    }
    if (g == 0) { as2[d] = ps; ad2[d] = pd; }
}

// ---------------- GAT layer 2 aggregation in g1-space (packed bf16; no max-shift) ----------------
__global__ void k_agg1y(const int* rowptr, const int* colidx, const unsigned int* hb,
                        const float* as_, const float* ad_, float* yacc) {
    int t = threadIdx.x;
    int d = blockIdx.x * 4 + (t >> 6);   // wave per node
    int c = t & 63;
    float adv = ad_[d];
    int p0 = rowptr[d], p1 = rowptr[d + 1];
    float den = 0.f, acc0 = 0.f, acc1 = 0.f;
    for (int pc = p0; pc < p1; pc += 4) {
        int sarr[4]; float ev[4]; unsigned int hv[4];
#pragma unroll
        for (int i = 0; i < 4; i++) {
            int pp = pc + i;
            sarr[i] = colidx[pp < p1 ? pp : p1 - 1];
        }
#pragma unroll
        for (int i = 0; i < 4; i++) {
            ev[i] = as_[sarr[i]];
            hv[i] = hb[sarr[i] * 64 + c];
        }
#pragma unroll
        for (int i = 0; i < 4; i++) {
            if (pc + i < p1) {
                float e = ev[i] + adv;
                e = e >= 0.f ? e : 0.2f * e;
                float w = __expf(e);
                den += w;
                acc0 += w * __uint_as_float(hv[i] << 16);
                acc1 += w * __uint_as_float(hv[i] & 0xFFFF0000u);
            }
        }
    }
    float inv = 1.f / (den + 1e-16f);
    ((float2*)yacc)[d * 64 + c] = (float2){acc0 * inv, acc1 * inv};
}

// ---------------- layer-2 matmul + fused mean-pool scatter: sums += elu(yacc @ W2 + b2) ----------------
#define ASTR 136
__global__ __launch_bounds__(256, 2) void k_g2mm(
    const float* yacc, const short* Bh, const short* Bl, const float* b2,
    const int* batch, float* sums) {
    __shared__ __align__(16) short Ah[64 * ASTR];
    __shared__ __align__(16) short Al[64 * ASTR];
    __shared__ int sb[64];
    int t = threadIdx.x;
    int m0 = blockIdx.x * 64;
    int wv = t >> 6, lane = t & 63;
    int ln15 = lane & 15, quad = lane >> 4;

    if (t < 64) sb[t] = batch[m0 + t];
    for (int i = t; i < 64 * 32; i += 256) {
        int row = i >> 5, c4 = (i & 31) * 4;
        float4 v = *(const float4*)&yacc[(m0 + row) * 128 + c4];
        short4v hi, lo;
        hi.x = f2bf(v.x); lo.x = f2bf(v.x - bf2f(hi.x));
        hi.y = f2bf(v.y); lo.y = f2bf(v.y - bf2f(hi.y));
        hi.z = f2bf(v.z); lo.z = f2bf(v.z - bf2f(hi.z));
        hi.w = f2bf(v.w); lo.w = f2bf(v.w - bf2f(hi.w));
        *(short4v*)&Ah[row * ASTR + c4] = hi;
        *(short4v*)&Al[row * ASTR + c4] = lo;
    }
    __syncthreads();

    f32x4 acc[8];
#pragma unroll
    for (int nt = 0; nt < 8; nt++) acc[nt] = (f32x4){0.f, 0.f, 0.f, 0.f};
    int arow = wv * 16 + ln15;
#pragma unroll
    for (int kb = 0; kb < 4; kb++) {
        int koff = kb * 32 + quad * 8;
        short8 a_hi = *(const short8*)&Ah[arow * ASTR + koff];
        short8 a_lo = *(const short8*)&Al[arow * ASTR + koff];
#pragma unroll
        for (int nt = 0; nt < 8; nt++) {
            short8 bh = *(const short8*)&Bh[((kb * 8 + nt) * 64 + lane) * 8];
            short8 bl = *(const short8*)&Bl[((kb * 8 + nt) * 64 + lane) * 8];
            acc[nt] = __builtin_amdgcn_mfma_f32_16x16x32_bf16(a_hi, bh, acc[nt], 0, 0, 0);
            acc[nt] = __builtin_amdgcn_mfma_f32_16x16x32_bf16(a_hi, bl, acc[nt], 0, 0, 0);
            acc[nt] = __builtin_amdgcn_mfma_f32_16x16x32_bf16(a_lo, bh, acc[nt], 0, 0, 0);
        }
    }
    // epilogue: bias+elu, then segmented (sorted-batch) atomic accumulate into sums
    int rbase = wv * 16 + quad * 4;
#pragma unroll
    for (int nt = 0; nt < 8; nt++) {
        int col = nt * 16 + ln15;
        float bias = b2[col];
        float run = 0.f;
        int cg = sb[rbase];
#pragma unroll
        for (int r = 0; r < 4; r++) {
            float v = acc[nt][r] + bias;
            v = v > 0.f ? v : __expf(v) - 1.f;
            int g = sb[rbase + r];
            if (g != cg) {
                atomicAdd(&sums[cg * 128 + col], run);
                run = 0.f; cg = g;
            }
            run += v;
        }
        atomicAdd(&sums[cg * 128 + col], run);
    }
}

// ---------------- tail: pmax tile-reduce + cnt via binary search + head MLP ----------------
__global__ __launch_bounds__(512) void k_tail(
    const float* pmaxp, const float* bk2, const float* Wp, const float* bp,
    const float* sums, const int* batch, const float* Wd, const float* bd,
    const float* Wf1, const float* bf1, const float* Wf2, const float* bf2,
    const float* Wo, const float* bo, float* out) {
    __shared__ float spm[128];
    __shared__ float in2[512];
    __shared__ float part1[512];
    __shared__ float hh[128];
    __shared__ float part2[512];
    __shared__ float h2s[64];
    __shared__ int sLo, sHi;
    int g = blockIdx.x, t = threadIdx.x;

    if (t < 128) {   // reduce 17 tiles -> bias+elu once (elu monotonic)
        float m = -1e30f;
#pragma unroll
        for (int tt = 0; tt < NTILE; tt++)
            m = fmaxf(m, pmaxp[(g * NTILE + tt) * 128 + t]);
        float v = m + bk2[t];
        spm[t] = v > 0.f ? v : __expf(v) - 1.f;
    } else if (t == 128 || t == 129) {
        // cnt[g] = lower_bound(batch, g+1) - lower_bound(batch, g)  (batch sorted)
        int target = g + (t - 128);
        int lo = 0, hi = NN;
        while (lo < hi) {
            int mid = (lo + hi) >> 1;
            if (batch[mid] < target) lo = mid + 1; else hi = mid;
        }
        if (t == 128) sLo = lo; else sHi = lo;
    }
    __syncthreads();

    if (t < 256) {
        float pacc = bp[t];
#pragma unroll 8
        for (int i = 0; i < 128; i++) pacc += spm[i] * Wp[i * 256 + t];
        in2[256 + t] = pacc > 0.f ? pacc : 0.f;
    } else {
        int o = t - 256;
        float c = (float)(sHi - sLo); c = c < 1.f ? 1.f : c;
        float inv = 1.f / c;
        float dacc = bd[o];
#pragma unroll 8
        for (int i = 0; i < 128; i++) dacc += sums[g * 128 + i] * inv * Wd[i * 256 + o];
        in2[o] = dacc > 0.f ? dacc : 0.f;
    }
    __syncthreads();

    {
        int o = t >> 2, ks = t & 3;
        float p = 0.f;
        int c0 = ks * 128;
#pragma unroll 8
        for (int cc = c0; cc < c0 + 128; cc++) p += in2[cc] * Wf1[cc * 128 + o];
        part1[t] = p;
    }
    __syncthreads();
    if (t < 128) {
        float a = bf1[t] + part1[t * 4] + part1[t * 4 + 1] + part1[t * 4 + 2] + part1[t * 4 + 3];
        hh[t] = a > 0.f ? a : 0.f;
    }
    __syncthreads();

    {
        int o = t >> 3, ks = t & 7;
        float p = 0.f;
        int c0 = ks * 16;
#pragma unroll
        for (int cc = c0; cc < c0 + 16; cc++) p += hh[cc] * Wf2[cc * 64 + o];
        part2[t] = p;
    }
    __syncthreads();
    if (t < 64) {
        float a = bf2[t];
#pragma unroll
        for (int k = 0; k < 8; k++) a += part2[t * 8 + k];
        h2s[t] = a > 0.f ? a : 0.f;
    }
    __syncthreads();

    if (t < 64) {
        float p = h2s[t] * Wo[t];
#pragma unroll
        for (int off = 32; off > 0; off >>= 1) p += __shfl_down(p, off, 64);
        if (t == 0) out[g] = p + bo[0];
    }
}

extern "C" void kernel_launch(void* const* d_in, const int* in_sizes, int n_in,
                              void* d_out, int out_size, void* d_ws, size_t ws_size,
                              hipStream_t stream) {
    (void)in_sizes; (void)n_in; (void)out_size; (void)ws_size;
    const float* x   = (const float*)d_in[0];
    const int* ei    = (const int*)d_in[1];
    const int* batch = (const int*)d_in[2];
    const int* seq   = (const int*)d_in[3];
    const float* W1  = (const float*)d_in[4];
    const float* a_s1 = (const float*)d_in[5];
    const float* a_d1 = (const float*)d_in[6];
    const float* b1  = (const float*)d_in[7];
    const float* W2  = (const float*)d_in[8];
    const float* a_s2 = (const float*)d_in[9];
    const float* a_d2 = (const float*)d_in[10];
    const float* b2  = (const float*)d_in[11];
    const float* Wd  = (const float*)d_in[12];
    const float* bd  = (const float*)d_in[13];
    const float* Pe  = (const float*)d_in[14];
    const float* K1  = (const float*)d_in[15];
    const float* bk1 = (const float*)d_in[16];
    const float* K2  = (const float*)d_in[17];
    const float* bk2 = (const float*)d_in[18];
    const float* Wp  = (const float*)d_in[19];
    const float* bp  = (const float*)d_in[20];
    const float* Wf1 = (const float*)d_in[21];
    const float* bf1 = (const float*)d_in[22];
    const float* Wf2 = (const float*)d_in[23];
    const float* bf2 = (const float*)d_in[24];
    const float* Wo  = (const float*)d_in[25];
    const float* bo  = (const float*)d_in[26];
    float* out = (float*)d_out;

    float* w = (float*)d_ws;
    float* g1bf = w; w += NN * 64;    // packed-bf16 uint[NN*64]
    float* yacc = w; w += NN * 128;
    float* as2  = w; w += NN;
    float* ad2  = w; w += NN;
    float* sums = w; w += NG * 128;
    float* pmaxp = w; w += NB * NTILE * 128;   // per-tile raw max
    float* rec  = w; w += NN * 16;             // packed {x[5], as1[2], ad1[2]} per node
    float* wvec = w; w += 512;
    short* Bswz2 = (short*)w; w += 320 * 128 / 2;
    short* Bh2  = (short*)w; w += 128 * 128 / 2;
    short* Bl2  = (short*)w; w += 128 * 128 / 2;
    float* M1   = w; w += 22 * 3 * 64;
    int* deg    = (int*)w; w += NN;
    int* cursor = (int*)w; w += NN;
    int* part   = (int*)w; w += 128;
    int* ctr    = (int*)w; w += 8;
    int* rowptr = (int*)w; w += NN + 8;
    int* colidx = (int*)w; w += ETOT;

    unsigned int* g1b = (unsigned int*)g1bf;

    // D1: init + weight prep
    hipLaunchKernelGGL(k_init_prep, dim3(256 + 160), dim3(256), 0, stream,
                       deg, cursor, sums, ctr,
                       K1, K2, W2, Pe, W1, a_s1, a_d1, a_s2, a_d2,
                       Bswz2, Bh2, Bl2, M1, wvec);

    // D2: protein + CSR count + as1/rec
    hipLaunchKernelGGL(k_prot_cnt_as1, dim3(PROT_BLKS + CNT_BLKS + AS1_BLKS), dim3(256), 0, stream,
                       seq, M1, bk1, Bswz2, pmaxp,
                       ei, deg, x, wvec, rec);

    // D3: merged CSR scan (96 peers)
    hipLaunchKernelGGL(k_scan, dim3(NN / 256), dim3(256), 0, stream, deg, rowptr, part, ctr);

    // D4: scatter
    hipLaunchKernelGGL(k_scatter, dim3(ETOT / 256), dim3(256), 0, stream, ei, rowptr, cursor, colidx);

    // D5: GAT layer 1 aggregation (rec-space) + fused W1
    hipLaunchKernelGGL(k_agg2x, dim3(NN / 16), dim3(256), 0, stream,
                       rowptr, colidx, rec, W1, b1, wvec, g1b, as2, ad2);

    // D6: GAT layer 2 aggregation
    hipLaunchKernelGGL(k_agg1y, dim3(NN / 4), dim3(256), 0, stream,
                       rowptr, colidx, g1b, as2, ad2, yacc);

    // D7: W2 matmul + fused mean-pool scatter
    hipLaunchKernelGGL(k_g2mm, dim3(NN / 64), dim3(256), 0, stream,
                       yacc, Bh2, Bl2, b2, batch, sums);

    // D8: tail (pmax tile-reduce + binary-search cnt)
    hipLaunchKernelGGL(k_tail, dim3(NG), dim3(512), 0, stream,
                       pmaxp, bk2, Wp, bp, sums, batch, Wd, bd, Wf1, bf1, Wf2, bf2, Wo, bo, out);
}

// Round 10
// 270.824 us; speedup vs baseline: 1.2276x; 1.0029x over previous
//
#include <hip/hip_runtime.h>
#include <hip/hip_bf16.h>
#include <math.h>

#define NN 24576
#define NE 98304
#define ETOT (NE + NN)
#define NG 512
#define NB 512
#define LL 1000
#define TL 60
#define NTILE 17
#define PROT_BLKS (NB * NTILE)
#define CNT_BLKS (ETOT / 256)
#define AS1_BLKS (NN * 2 / 256)

typedef __attribute__((ext_vector_type(8))) short short8;
typedef __attribute__((ext_vector_type(4))) short short4v;
typedef __attribute__((ext_vector_type(4))) float f32x4;

__device__ inline short f2bf(float x) {
    union { __hip_bfloat16 b; short s; } u;
    u.b = __float2bfloat16(x);
    return u.s;
}

__device__ inline float bf2f(short s) {
    return __uint_as_float(((unsigned)(unsigned short)s) << 16);
}

// ---------------- D1: init + weight prep (disjoint block ranges) ----------------
__global__ void k_init_prep(int* deg, int* cursor, float* sums, int* ctr,
                            const float* K1, const float* K2, const float* W2, const float* Pe,
                            const float* W1, const float* as1c, const float* ad1c,
                            const float* as2c, const float* ad2c, const float* bk1,
                            short* Bswz2, short* Bh2, short* Bl2, float* M01, float* M2x,
                            float* wvec) {
    int bid = blockIdx.x, t = threadIdx.x;
    if (bid < 256) {                       // init body
        int i = bid * 256 + t;
        if (i < NN) { deg[i] = 0; cursor[i] = 0; }
        if (i < NG * 128) sums[i] = 0.f;
        if (i < 2) ctr[i] = 0;
        return;
    }
    int idx = (bid - 256) * 256 + t;       // prep body (160 blocks)
    if (idx < 20) {             // was1 [0..9], wad1 [10..19]
        int q = idx % 10, hd = q / 5, f = q % 5;
        const float* av = (idx < 10) ? as1c : ad1c;
        float s = 0.f;
        for (int c = 0; c < 64; c++) s += W1[f * 128 + hd * 64 + c] * av[hd * 64 + c];
        wvec[idx < 10 ? q : 10 + q] = s;
    }
    if (idx >= 32 && idx < 288) {   // wa_s2 [32..159], wa_d2 [160..287]
        int q = idx - 32;
        int kk = q & 127;
        const float* av = (q < 128) ? as2c : ad2c;
        float s = 0.f;
        for (int n2 = 0; n2 < 128; n2++) s += W2[kk * 128 + n2] * av[n2];
        wvec[idx] = s;
    }
    if (idx < 506 * 64) {       // M01 pair table: taps {0,1} + bias. row = (t0+1)*22 + t1
        int pr = idx >> 6, oc = idx & 63;
        int tA = pr / 22 - 1, tB = pr % 22;
        float s = bk1[oc];
        if (tA >= 0) {
            for (int ic = 0; ic < 64; ic++) s += K1[oc * 192 + ic * 3 + 0] * Pe[tA * 64 + ic];
        }
        for (int ic = 0; ic < 64; ic++) s += K1[oc * 192 + ic * 3 + 1] * Pe[tB * 64 + ic];
        M01[idx] = s;
    }
    if (idx < 23 * 64) {        // M2x single table: tap 2. row = (t2+1), row 0 = zeros
        int tr = idx >> 6, oc = idx & 63;
        float s = 0.f;
        if (tr >= 1) {
            int tk = tr - 1;
            for (int ic = 0; ic < 64; ic++) s += K1[oc * 192 + ic * 3 + 2] * Pe[tk * 64 + ic];
        }
        M2x[idx] = s;
    }
    if (idx < 320 * 128) {      // B2
        int j = idx & 7, lane = (idx >> 3) & 63, rest = idx >> 9;
        int nt = rest & 7, kb = rest >> 3;
        int k = kb * 32 + ((lane >> 4) << 3) + j;
        int n = nt * 16 + (lane & 15);
        int kk = k / 64, i = k % 64;
        Bswz2[idx] = f2bf(K2[n * 320 + i * 5 + kk]);
    }
    if (idx < 128 * 128) {      // W2 hi/lo
        int j = idx & 7, lane = (idx >> 3) & 63, rest = idx >> 9;
        int nt = rest & 7, kb = rest >> 3;
        int k = kb * 32 + ((lane >> 4) << 3) + j;
        int n = nt * 16 + (lane & 15);
        float v = W2[k * 128 + n];
        short hh = f2bf(v);
        Bh2[idx] = hh;
        Bl2[idx] = f2bf(v - bf2f(hh));
    }
}

// ---------------- D2: protein (pair-table conv1 + MFMA conv2) + CSR count + as1/rec ----------------
#define SSTR 72
__global__ __launch_bounds__(256, 6) void k_prot_cnt_as1(
    const int* seq, const float* M01, const float* M2x,
    const short* Bswz2, float* pmaxp,
    const int* ei, int* deg,
    const float* x, const float* wvec, float* rec) {
    int bid = blockIdx.x;
    int t = threadIdx.x;

    if (bid >= PROT_BLKS) {
        int rb = bid - PROT_BLKS;
        if (rb < CNT_BLKS) {               // CSR count
            int e = rb * 256 + t;
            int d = (e < NE) ? ei[NE + e] : e - NE;
            atomicAdd(&deg[d], 1);
        } else {                           // as1 + packed per-node record
            int idx = (rb - CNT_BLKS) * 256 + t;   // NN*2
            int n = idx >> 1, hd = idx & 1;
            float xv[5];
            float s = 0.f, dv = 0.f;
#pragma unroll
            for (int f = 0; f < 5; f++) {
                xv[f] = x[n * 5 + f];
                s += xv[f] * wvec[hd * 5 + f];
                dv += xv[f] * wvec[10 + hd * 5 + f];
            }
            float* rr = &rec[n * 16];
            if (hd == 0) {
#pragma unroll
                for (int f = 0; f < 5; f++) rr[f] = xv[f];
                rr[5] = s; rr[7] = dv;
            } else {
                rr[6] = s; rr[8] = dv;
            }
        }
        return;
    }

    // ---- protein body: tile of TL=60 positions ----
    __shared__ __align__(16) short s1[68 * SSTR];   // conv1 out rows 0..67 (64 computed + 4 zero)

    int b = bid / NTILE;
    int tile = bid - b * NTILE;
    int t0 = tile * TL;

    if (t < 36) {   // zero s1 rows 64..67 (4*72=288 shorts)
        *(short8*)&s1[64 * SSTR + t * 8] = (short8){0, 0, 0, 0, 0, 0, 0, 0};
    }

    // conv1 via pair+single token tables (bias folded into pair table)
    {
        int q = t >> 2, c0 = (t & 3) << 4;   // 64 rows x 4 col-blocks of 16
        int l = t0 - 2 + q;
        short tmp[16];
        if (l >= 0 && l < LL) {
            int t1k = seq[b * LL + l];
            int t0k = (l > 0) ? seq[b * LL + l - 1] : -1;
            int t2k = (l + 1 < LL) ? seq[b * LL + l + 1] : -1;
            const float4* p01 = (const float4*)&M01[((t0k + 1) * 22 + t1k) * 64 + c0];
            const float4* p2  = (const float4*)&M2x[(t2k + 1) * 64 + c0];
#pragma unroll
            for (int j = 0; j < 4; j++) {
                float4 a = p01[j];
                float4 bb4 = p2[j];
                float vv[4] = {a.x + bb4.x, a.y + bb4.y, a.z + bb4.z, a.w + bb4.w};
#pragma unroll
                for (int r = 0; r < 4; r++) {
                    float xv = vv[r];
                    xv = xv > 0.f ? xv : __expf(xv) - 1.f;
                    tmp[j * 4 + r] = f2bf(xv);
                }
            }
        } else {
#pragma unroll
            for (int j = 0; j < 16; j++) tmp[j] = 0;
        }
        *(short8*)&s1[q * SSTR + c0] = *(short8*)&tmp[0];
        *(short8*)&s1[q * SSTR + c0 + 8] = *(short8*)&tmp[8];
    }
    __syncthreads();

    // conv2 MFMA. M=64 (4 mt), N=128 (8 nt), K=320 (10 kb); wave wv owns nt = {2wv, 2wv+1}
    int wv = t >> 6, lane = t & 63;
    int ln15 = lane & 15, quad = lane >> 4;

    f32x4 acc2[4][2];
#pragma unroll
    for (int mi = 0; mi < 4; mi++)
#pragma unroll
        for (int ni = 0; ni < 2; ni++) acc2[mi][ni] = (f32x4){0.f, 0.f, 0.f, 0.f};
#pragma unroll 2
    for (int kb = 0; kb < 10; kb++) {
        int koff = kb * 32 + quad * 8;
        int kk = koff >> 6, i0 = koff & 63;
        short8 a[4], bb[2];
#pragma unroll
        for (int mi = 0; mi < 4; mi++)
            a[mi] = *(const short8*)&s1[(mi * 16 + ln15 + kk) * SSTR + i0];
#pragma unroll
        for (int ni = 0; ni < 2; ni++)
            bb[ni] = *(const short8*)&Bswz2[((kb * 8 + wv * 2 + ni) * 64 + lane) * 8];
#pragma unroll
        for (int mi = 0; mi < 4; mi++)
#pragma unroll
            for (int ni = 0; ni < 2; ni++)
                acc2[mi][ni] = __builtin_amdgcn_mfma_f32_16x16x32_bf16(a[mi], bb[ni], acc2[mi][ni], 0, 0, 0);
    }

    // epilogue: masked raw max, plain store per (b,tile,col) — reduced in k_tail
#pragma unroll
    for (int ni = 0; ni < 2; ni++) {
        int col = (wv * 2 + ni) * 16 + ln15;
        float mx = -1e30f;
#pragma unroll
        for (int mi = 0; mi < 4; mi++) {
#pragma unroll
            for (int r = 0; r < 4; r++) {
                int p = mi * 16 + quad * 4 + r;
                if (p < TL && t0 + p < LL) mx = fmaxf(mx, acc2[mi][ni][r]);
            }
        }
        mx = fmaxf(mx, __shfl_xor(mx, 16, 64));
        mx = fmaxf(mx, __shfl_xor(mx, 32, 64));
        if (quad == 0) pmaxp[(b * NTILE + tile) * 128 + col] = mx;
    }
}

// ---------------- D3: merged CSR scan (96 peer blocks, spin barrier; R6-proven) ----------------
__global__ void k_scan(const int* deg, int* rowptr, int* part, int* ctr) {
    __shared__ int s[256];
    __shared__ int sp[96];
    int b = blockIdx.x, t = threadIdx.x, i = b * 256 + t;
    int v = deg[i];
    s[t] = v;
    __syncthreads();
    for (int o = 1; o < 256; o <<= 1) {
        int x2 = (t >= o) ? s[t - o] : 0;
        __syncthreads();
        s[t] += x2;
        __syncthreads();
    }
    int excl = s[t] - v;
    if (t == 255) {
        part[b] = s[t];
        __threadfence();
        atomicAdd(ctr, 1);
    }
    if (t == 0) {
        while (__hip_atomic_load(ctr, __ATOMIC_ACQUIRE, __HIP_MEMORY_SCOPE_AGENT) < 96) {}
    }
    __syncthreads();
    if (t < 96) sp[t] = __hip_atomic_load(&part[t], __ATOMIC_RELAXED, __HIP_MEMORY_SCOPE_AGENT);
    __syncthreads();
    int pref = 0;
    for (int i2 = 0; i2 < b; i2++) pref += sp[i2];
    rowptr[i] = excl + pref;
    if (i == 0) rowptr[NN] = ETOT;
}

// ---------------- D4: scatter ----------------
__global__ void k_scatter(const int* ei, const int* rowptr, int* cursor, int* colidx) {
    int e = blockIdx.x * 256 + threadIdx.x;
    if (e >= ETOT) return;
    int s, d;
    if (e < NE) { s = ei[e]; d = ei[NE + e]; }
    else { s = d = e - NE; }
    int pos = atomicAdd(&cursor[d], 1);
    colidx[rowptr[d] + pos] = s;
}

// ---------------- GAT layer 1: x-space aggregation + fused W1 (packed 64B node records) ----------------
__global__ void k_agg2x(const int* rowptr, const int* colidx, const float* rec,
                        const float* W1, const float* b1, const float* wvec,
                        unsigned int* g1b, float* as2, float* ad2) {
    __shared__ float sW[640];
    __shared__ float sb1[128];
    __shared__ float swa[256];
    int t = threadIdx.x;
    for (int i = t; i < 640; i += 256) sW[i] = W1[i];
    if (t < 128) { sb1[t] = b1[t]; swa[t] = wvec[32 + t]; swa[128 + t] = wvec[160 + t]; }
    __syncthreads();

    int d = blockIdx.x * 16 + (t >> 4);   // grid = NN/16
    int g = t & 15;
    int hd = (g < 5) ? 0 : 1;
    int f = (g < 5) ? g : g - 5;
    float adv = rec[d * 16 + 7 + hd];
    int p0 = rowptr[d], p1 = rowptr[d + 1];
    float den = 0.f, acc = 0.f;
    if (g < 10) {
        for (int pc = p0; pc < p1; pc += 4) {
            int sarr[4]; float ev[4], xv[4];
#pragma unroll
            for (int i = 0; i < 4; i++) {
                int pp = pc + i;
                sarr[i] = colidx[pp < p1 ? pp : p1 - 1];
            }
#pragma unroll
            for (int i = 0; i < 4; i++) {
                ev[i] = rec[sarr[i] * 16 + 5 + hd];
                xv[i] = rec[sarr[i] * 16 + f];
            }
#pragma unroll
            for (int i = 0; i < 4; i++) {
                if (pc + i < p1) {
                    float e = ev[i] + adv;
                    e = e >= 0.f ? e : 0.2f * e;
                    float w = __expf(e);
                    den += w;
                    acc += w * xv[i];
                }
            }
        }
    }
    float xn = acc / (den + 1e-16f);
    int gb = (t & 63) & ~15;
    int hcol = g >> 3;
    float xs[5];
#pragma unroll
    for (int f2 = 0; f2 < 5; f2++)
        xs[f2] = __shfl(xn, gb + hcol * 5 + f2, 64);
    float ps = 0.f, pd = 0.f;
    float g1v[8];
#pragma unroll
    for (int k = 0; k < 8; k++) {
        int col = g * 8 + k;
        float v = sb1[col];
#pragma unroll
        for (int f2 = 0; f2 < 5; f2++) v += xs[f2] * sW[f2 * 128 + col];
        v = v > 0.f ? v : __expf(v) - 1.f;
        g1v[k] = v;
        ps += v * swa[col];
        pd += v * swa[128 + col];
    }
    uint4 pk;
    pk.x = ((unsigned)(unsigned short)f2bf(g1v[1]) << 16) | (unsigned)(unsigned short)f2bf(g1v[0]);
    pk.y = ((unsigned)(unsigned short)f2bf(g1v[3]) << 16) | (unsigned)(unsigned short)f2bf(g1v[2]);
    pk.z = ((unsigned)(unsigned short)f2bf(g1v[5]) << 16) | (unsigned)(unsigned short)f2bf(g1v[4]);
    pk.w = ((unsigned)(unsigned short)f2bf(g1v[7]) << 16) | (unsigned)(unsigned short)f2bf(g1v[6]);
    *(uint4*)&g1b[d * 64 + g * 4] = pk;
#pragma unroll
    for (int msk = 1; msk < 16; msk <<= 1) {
        ps += __shfl_xor(ps, msk, 64);
        pd += __shfl_xor(pd, msk, 64);
    }
    if (g == 0) { as2[d] = ps; ad2[d] = pd; }
}

// ---------------- GAT layer 2 aggregation in g1-space; writes split-bf16 hi/lo directly ----------------
__global__ void k_agg1y(const int* rowptr, const int* colidx, const unsigned int* hb,
                        const float* as_, const float* ad_,
                        unsigned int* yH, unsigned int* yL) {
    int t = threadIdx.x;
    int d = blockIdx.x * 4 + (t >> 6);   // wave per node
    int c = t & 63;
    float adv = ad_[d];
    int p0 = rowptr[d], p1 = rowptr[d + 1];
    float den = 0.f, acc0 = 0.f, acc1 = 0.f;
    for (int pc = p0; pc < p1; pc += 4) {
        int sarr[4]; float ev[4]; unsigned int hv[4];
#pragma unroll
        for (int i = 0; i < 4; i++) {
            int pp = pc + i;
            sarr[i] = colidx[pp < p1 ? pp : p1 - 1];
        }
#pragma unroll
        for (int i = 0; i < 4; i++) {
            ev[i] = as_[sarr[i]];
            hv[i] = hb[sarr[i] * 64 + c];
        }
#pragma unroll
        for (int i = 0; i < 4; i++) {
            if (pc + i < p1) {
                float e = ev[i] + adv;
                e = e >= 0.f ? e : 0.2f * e;
                float w = __expf(e);
                den += w;
                acc0 += w * __uint_as_float(hv[i] << 16);
                acc1 += w * __uint_as_float(hv[i] & 0xFFFF0000u);
            }
        }
    }
    float inv = 1.f / (den + 1e-16f);
    float v0 = acc0 * inv, v1 = acc1 * inv;
    short h0 = f2bf(v0), l0 = f2bf(v0 - bf2f(h0));
    short h1 = f2bf(v1), l1 = f2bf(v1 - bf2f(h1));
    yH[d * 64 + c] = ((unsigned)(unsigned short)h1 << 16) | (unsigned)(unsigned short)h0;
    yL[d * 64 + c] = ((unsigned)(unsigned short)l1 << 16) | (unsigned)(unsigned short)l0;
}

// ---------------- layer-2 matmul + fused mean-pool scatter: sums += elu(y @ W2 + b2) ----------------
#define ASTR 136
__global__ __launch_bounds__(256, 2) void k_g2mm(
    const unsigned int* yH, const unsigned int* yL, const short* Bh, const short* Bl,
    const float* b2, const int* batch, float* sums) {
    __shared__ __align__(16) short Ah[64 * ASTR];
    __shared__ __align__(16) short Al[64 * ASTR];
    __shared__ int sb[64];
    int t = threadIdx.x;
    int m0 = blockIdx.x * 64;
    int wv = t >> 6, lane = t & 63;
    int ln15 = lane & 15, quad = lane >> 4;

    if (t < 64) sb[t] = batch[m0 + t];
    for (int i = t; i < 64 * 16; i += 256) {   // pure uint4 copies (split done in agg1y)
        int row = i >> 4, cu = (i & 15) * 4;
        *(uint4*)&Ah[row * ASTR + cu * 2] = *(const uint4*)&yH[(m0 + row) * 64 + cu];
        *(uint4*)&Al[row * ASTR + cu * 2] = *(const uint4*)&yL[(m0 + row) * 64 + cu];
    }
    __syncthreads();

    f32x4 acc[8];
#pragma unroll
    for (int nt = 0; nt < 8; nt++) acc[nt] = (f32x4){0.f, 0.f, 0.f, 0.f};
    int arow = wv * 16 + ln15;
#pragma unroll
    for (int kb = 0; kb < 4; kb++) {
        int koff = kb * 32 + quad * 8;
        short8 a_hi = *(const short8*)&Ah[arow * ASTR + koff];
        short8 a_lo = *(const short8*)&Al[arow * ASTR + koff];
#pragma unroll
        for (int nt = 0; nt < 8; nt++) {
            short8 bh = *(const short8*)&Bh[((kb * 8 + nt) * 64 + lane) * 8];
            short8 bl = *(const short8*)&Bl[((kb * 8 + nt) * 64 + lane) * 8];
            acc[nt] = __builtin_amdgcn_mfma_f32_16x16x32_bf16(a_hi, bh, acc[nt], 0, 0, 0);
            acc[nt] = __builtin_amdgcn_mfma_f32_16x16x32_bf16(a_hi, bl, acc[nt], 0, 0, 0);
            acc[nt] = __builtin_amdgcn_mfma_f32_16x16x32_bf16(a_lo, bh, acc[nt], 0, 0, 0);
        }
    }
    // epilogue: bias+elu, then segmented (sorted-batch) atomic accumulate into sums
    int rbase = wv * 16 + quad * 4;
#pragma unroll
    for (int nt = 0; nt < 8; nt++) {
        int col = nt * 16 + ln15;
        float bias = b2[col];
        float run = 0.f;
        int cg = sb[rbase];
#pragma unroll
        for (int r = 0; r < 4; r++) {
            float v = acc[nt][r] + bias;
            v = v > 0.f ? v : __expf(v) - 1.f;
            int g = sb[rbase + r];
            if (g != cg) {
                atomicAdd(&sums[cg * 128 + col], run);
                run = 0.f; cg = g;
            }
            run += v;
        }
        atomicAdd(&sums[cg * 128 + col], run);
    }
}

// ---------------- tail: pmax tile-reduce + cnt via binary search + head MLP ----------------
__global__ __launch_bounds__(512) void k_tail(
    const float* pmaxp, const float* bk2, const float* Wp, const float* bp,
    const float* sums, const int* batch, const float* Wd, const float* bd,
    const float* Wf1, const float* bf1, const float* Wf2, const float* bf2,
    const float* Wo, const float* bo, float* out) {
    __shared__ float spm[128];
    __shared__ float in2[512];
    __shared__ float part1[512];
    __shared__ float hh[128];
    __shared__ float part2[512];
    __shared__ float h2s[64];
    __shared__ int sLo, sHi;
    int g = blockIdx.x, t = threadIdx.x;

    if (t < 128) {   // reduce 17 tiles -> bias+elu once (elu monotonic)
        float m = -1e30f;
#pragma unroll
        for (int tt = 0; tt < NTILE; tt++)
            m = fmaxf(m, pmaxp[(g * NTILE + tt) * 128 + t]);
        float v = m + bk2[t];
        spm[t] = v > 0.f ? v : __expf(v) - 1.f;
    } else if (t == 128 || t == 129) {
        // cnt[g] = lower_bound(batch, g+1) - lower_bound(batch, g)  (batch sorted)
        int target = g + (t - 128);
        int lo = 0, hi = NN;
        while (lo < hi) {
            int mid = (lo + hi) >> 1;
            if (batch[mid] < target) lo = mid + 1; else hi = mid;
        }
        if (t == 128) sLo = lo; else sHi = lo;
    }
    __syncthreads();

    if (t < 256) {
        float pacc = bp[t];
#pragma unroll 8
        for (int i = 0; i < 128; i++) pacc += spm[i] * Wp[i * 256 + t];
        in2[256 + t] = pacc > 0.f ? pacc : 0.f;
    } else {
        int o = t - 256;
        float c = (float)(sHi - sLo); c = c < 1.f ? 1.f : c;
        float inv = 1.f / c;
        float dacc = bd[o];
#pragma unroll 8
        for (int i = 0; i < 128; i++) dacc += sums[g * 128 + i] * inv * Wd[i * 256 + o];
        in2[o] = dacc > 0.f ? dacc : 0.f;
    }
    __syncthreads();

    {
        int o = t >> 2, ks = t & 3;
        float p = 0.f;
        int c0 = ks * 128;
#pragma unroll 8
        for (int cc = c0; cc < c0 + 128; cc++) p += in2[cc] * Wf1[cc * 128 + o];
        part1[t] = p;
    }
    __syncthreads();
    if (t < 128) {
        float a = bf1[t] + part1[t * 4] + part1[t * 4 + 1] + part1[t * 4 + 2] + part1[t * 4 + 3];
        hh[t] = a > 0.f ? a : 0.f;
    }
    __syncthreads();

    {
        int o = t >> 3, ks = t & 7;
        float p = 0.f;
        int c0 = ks * 16;
#pragma unroll
        for (int cc = c0; cc < c0 + 16; cc++) p += hh[cc] * Wf2[cc * 64 + o];
        part2[t] = p;
    }
    __syncthreads();
    if (t < 64) {
        float a = bf2[t];
#pragma unroll
        for (int k = 0; k < 8; k++) a += part2[t * 8 + k];
        h2s[t] = a > 0.f ? a : 0.f;
    }
    __syncthreads();

    if (t < 64) {
        float p = h2s[t] * Wo[t];
#pragma unroll
        for (int off = 32; off > 0; off >>= 1) p += __shfl_down(p, off, 64);
        if (t == 0) out[g] = p + bo[0];
    }
}

extern "C" void kernel_launch(void* const* d_in, const int* in_sizes, int n_in,
                              void* d_out, int out_size, void* d_ws, size_t ws_size,
                              hipStream_t stream) {
    (void)in_sizes; (void)n_in; (void)out_size; (void)ws_size;
    const float* x   = (const float*)d_in[0];
    const int* ei    = (const int*)d_in[1];
    const int* batch = (const int*)d_in[2];
    const int* seq   = (const int*)d_in[3];
    const float* W1  = (const float*)d_in[4];
    const float* a_s1 = (const float*)d_in[5];
    const float* a_d1 = (const float*)d_in[6];
    const float* b1  = (const float*)d_in[7];
    const float* W2  = (const float*)d_in[8];
    const float* a_s2 = (const float*)d_in[9];
    const float* a_d2 = (const float*)d_in[10];
    const float* b2  = (const float*)d_in[11];
    const float* Wd  = (const float*)d_in[12];
    const float* bd  = (const float*)d_in[13];
    const float* Pe  = (const float*)d_in[14];
    const float* K1  = (const float*)d_in[15];
    const float* bk1 = (const float*)d_in[16];
    const float* K2  = (const float*)d_in[17];
    const float* bk2 = (const float*)d_in[18];
    const float* Wp  = (const float*)d_in[19];
    const float* bp  = (const float*)d_in[20];
    const float* Wf1 = (const float*)d_in[21];
    const float* bf1 = (const float*)d_in[22];
    const float* Wf2 = (const float*)d_in[23];
    const float* bf2 = (const float*)d_in[24];
    const float* Wo  = (const float*)d_in[25];
    const float* bo  = (const float*)d_in[26];
    float* out = (float*)d_out;

    float* w = (float*)d_ws;
    float* g1bf = w; w += NN * 64;    // packed-bf16 uint[NN*64]
    float* yHf  = w; w += NN * 64;    // split-bf16 hi, uint[NN*64]
    float* yLf  = w; w += NN * 64;    // split-bf16 lo, uint[NN*64]
    float* as2  = w; w += NN;
    float* ad2  = w; w += NN;
    float* sums = w; w += NG * 128;
    float* pmaxp = w; w += NB * NTILE * 128;   // per-tile raw max
    float* rec  = w; w += NN * 16;             // packed {x[5], as1[2], ad1[2]} per node
    float* wvec = w; w += 512;
    short* Bswz2 = (short*)w; w += 320 * 128 / 2;
    short* Bh2  = (short*)w; w += 128 * 128 / 2;
    short* Bl2  = (short*)w; w += 128 * 128 / 2;
    float* M01  = w; w += 506 * 64;
    float* M2x  = w; w += 23 * 64;
    int* deg    = (int*)w; w += NN;
    int* cursor = (int*)w; w += NN;
    int* part   = (int*)w; w += 128;
    int* ctr    = (int*)w; w += 8;
    int* rowptr = (int*)w; w += NN + 8;
    int* colidx = (int*)w; w += ETOT;

    unsigned int* g1b = (unsigned int*)g1bf;
    unsigned int* yH  = (unsigned int*)yHf;
    unsigned int* yL  = (unsigned int*)yLf;

    // D1: init + weight prep
    hipLaunchKernelGGL(k_init_prep, dim3(256 + 160), dim3(256), 0, stream,
                       deg, cursor, sums, ctr,
                       K1, K2, W2, Pe, W1, a_s1, a_d1, a_s2, a_d2, bk1,
                       Bswz2, Bh2, Bl2, M01, M2x, wvec);

    // D2: protein + CSR count + as1/rec
    hipLaunchKernelGGL(k_prot_cnt_as1, dim3(PROT_BLKS + CNT_BLKS + AS1_BLKS), dim3(256), 0, stream,
                       seq, M01, M2x, Bswz2, pmaxp,
                       ei, deg, x, wvec, rec);

    // D3: merged CSR scan (96 peers)
    hipLaunchKernelGGL(k_scan, dim3(NN / 256), dim3(256), 0, stream, deg, rowptr, part, ctr);

    // D4: scatter
    hipLaunchKernelGGL(k_scatter, dim3(ETOT / 256), dim3(256), 0, stream, ei, rowptr, cursor, colidx);

    // D5: GAT layer 1 aggregation (rec-space) + fused W1
    hipLaunchKernelGGL(k_agg2x, dim3(NN / 16), dim3(256), 0, stream,
                       rowptr, colidx, rec, W1, b1, wvec, g1b, as2, ad2);

    // D6: GAT layer 2 aggregation (split-bf16 output)
    hipLaunchKernelGGL(k_agg1y, dim3(NN / 4), dim3(256), 0, stream,
                       rowptr, colidx, g1b, as2, ad2, yH, yL);

    // D7: W2 matmul + fused mean-pool scatter
    hipLaunchKernelGGL(k_g2mm, dim3(NN / 64), dim3(256), 0, stream,
                       yH, yL, Bh2, Bl2, b2, batch, sums);

    // D8: tail (pmax tile-reduce + binary-search cnt)
    hipLaunchKernelGGL(k_tail, dim3(NG), dim3(512), 0, stream,
                       pmaxp, bk2, Wp, bp, sums, batch, Wd, bd, Wf1, bf1, Wf2, bf2, Wo, bo, out);
}

// Round 11
// 266.524 us; speedup vs baseline: 1.2474x; 1.0161x over previous
//
#include <hip/hip_runtime.h>
#include <hip/hip_bf16.h>
#include <math.h>

#define NN 24576
#define NE 98304
#define ETOT (NE + NN)
#define NG 512
#define NB 512
#define LL 1000
#define TL 60
#define NTILE 17
#define PROT_BLKS (NB * NTILE)
#define CNT_BLKS (ETOT / 256)
#define AS1_BLKS (NN * 2 / 256)

typedef __attribute__((ext_vector_type(8))) short short8;
typedef __attribute__((ext_vector_type(4))) short short4v;
typedef __attribute__((ext_vector_type(4))) float f32x4;

__device__ inline short f2bf(float x) {
    union { __hip_bfloat16 b; short s; } u;
    u.b = __float2bfloat16(x);
    return u.s;
}

__device__ inline float bf2f(short s) {
    return __uint_as_float(((unsigned)(unsigned short)s) << 16);
}

// ---------------- D1: init + weight prep (disjoint block ranges) ----------------
__global__ void k_init_prep(int* deg, int* cursor, float* sums, int* ctr,
                            const float* K1, const float* K2, const float* W2, const float* Pe,
                            const float* W1, const float* as1c, const float* ad1c,
                            const float* as2c, const float* ad2c, const float* bk1,
                            short* Bswz2, short* Bh2, short* Bl2, float* M01, float* M2x,
                            float* wvec) {
    int bid = blockIdx.x, t = threadIdx.x;
    if (bid < 256) {                       // init body
        int i = bid * 256 + t;
        if (i < NN) { deg[i] = 0; cursor[i] = 0; }
        if (i < NG * 128) sums[i] = 0.f;
        if (i < 2) ctr[i] = 0;
        return;
    }
    int idx = (bid - 256) * 256 + t;       // prep body (160 blocks)
    if (idx < 20) {             // was1 [0..9], wad1 [10..19]
        int q = idx % 10, hd = q / 5, f = q % 5;
        const float* av = (idx < 10) ? as1c : ad1c;
        float s = 0.f;
        for (int c = 0; c < 64; c++) s += W1[f * 128 + hd * 64 + c] * av[hd * 64 + c];
        wvec[idx < 10 ? q : 10 + q] = s;
    }
    if (idx >= 32 && idx < 288) {   // wa_s2 [32..159], wa_d2 [160..287]
        int q = idx - 32;
        int kk = q & 127;
        const float* av = (q < 128) ? as2c : ad2c;
        float s = 0.f;
        for (int n2 = 0; n2 < 128; n2++) s += W2[kk * 128 + n2] * av[n2];
        wvec[idx] = s;
    }
    if (idx < 506 * 64) {       // M01 pair table: taps {0,1} + bias. row = (t0+1)*22 + t1
        int pr = idx >> 6, oc = idx & 63;
        int tA = pr / 22 - 1, tB = pr % 22;
        float s = bk1[oc];
        if (tA >= 0) {
            for (int ic = 0; ic < 64; ic++) s += K1[oc * 192 + ic * 3 + 0] * Pe[tA * 64 + ic];
        }
        for (int ic = 0; ic < 64; ic++) s += K1[oc * 192 + ic * 3 + 1] * Pe[tB * 64 + ic];
        M01[idx] = s;
    }
    if (idx < 23 * 64) {        // M2x single table: tap 2. row = (t2+1), row 0 = zeros
        int tr = idx >> 6, oc = idx & 63;
        float s = 0.f;
        if (tr >= 1) {
            int tk = tr - 1;
            for (int ic = 0; ic < 64; ic++) s += K1[oc * 192 + ic * 3 + 2] * Pe[tk * 64 + ic];
        }
        M2x[idx] = s;
    }
    if (idx < 320 * 128) {      // B2
        int j = idx & 7, lane = (idx >> 3) & 63, rest = idx >> 9;
        int nt = rest & 7, kb = rest >> 3;
        int k = kb * 32 + ((lane >> 4) << 3) + j;
        int n = nt * 16 + (lane & 15);
        int kk = k / 64, i = k % 64;
        Bswz2[idx] = f2bf(K2[n * 320 + i * 5 + kk]);
    }
    if (idx < 128 * 128) {      // W2 hi/lo
        int j = idx & 7, lane = (idx >> 3) & 63, rest = idx >> 9;
        int nt = rest & 7, kb = rest >> 3;
        int k = kb * 32 + ((lane >> 4) << 3) + j;
        int n = nt * 16 + (lane & 15);
        float v = W2[k * 128 + n];
        short hh = f2bf(v);
        Bh2[idx] = hh;
        Bl2[idx] = f2bf(v - bf2f(hh));
    }
}

// ---------------- D2: protein (pair-table conv1 + MFMA conv2) + CSR count + as1/rec ----------------
#define SSTR 72
__global__ __launch_bounds__(256, 8) void k_prot_cnt_as1(
    const int* seq, const float* M01, const float* M2x,
    const short* Bswz2, float* pmaxp,
    const int* ei, int* deg,
    const float* x, const float* wvec, float* rec) {
    int bid = blockIdx.x;
    int t = threadIdx.x;

    if (bid >= PROT_BLKS) {
        int rb = bid - PROT_BLKS;
        if (rb < CNT_BLKS) {               // CSR count
            int e = rb * 256 + t;
            int d = (e < NE) ? ei[NE + e] : e - NE;
            atomicAdd(&deg[d], 1);
        } else {                           // as1 + packed per-node record
            int idx = (rb - CNT_BLKS) * 256 + t;   // NN*2
            int n = idx >> 1, hd = idx & 1;
            float xv[5];
            float s = 0.f, dv = 0.f;
#pragma unroll
            for (int f = 0; f < 5; f++) {
                xv[f] = x[n * 5 + f];
                s += xv[f] * wvec[hd * 5 + f];
                dv += xv[f] * wvec[10 + hd * 5 + f];
            }
            float* rr = &rec[n * 16];
            if (hd == 0) {
#pragma unroll
                for (int f = 0; f < 5; f++) rr[f] = xv[f];
                rr[5] = s; rr[7] = dv;
            } else {
                rr[6] = s; rr[8] = dv;
            }
        }
        return;
    }

    // ---- protein body: tile of TL=60 positions ----
    __shared__ __align__(16) short s1[68 * SSTR];   // conv1 out rows 0..67 (64 computed + 4 zero)

    int b = bid / NTILE;
    int tile = bid - b * NTILE;
    int t0 = tile * TL;

    if (t < 36) {   // zero s1 rows 64..67 (4*72=288 shorts)
        *(short8*)&s1[64 * SSTR + t * 8] = (short8){0, 0, 0, 0, 0, 0, 0, 0};
    }

    // conv1 via pair+single token tables (bias folded into pair table)
    {
        int q = t >> 2, c0 = (t & 3) << 4;   // 64 rows x 4 col-blocks of 16
        int l = t0 - 2 + q;
        short tmp[16];
        if (l >= 0 && l < LL) {
            int t1k = seq[b * LL + l];
            int t0k = (l > 0) ? seq[b * LL + l - 1] : -1;
            int t2k = (l + 1 < LL) ? seq[b * LL + l + 1] : -1;
            const float4* p01 = (const float4*)&M01[((t0k + 1) * 22 + t1k) * 64 + c0];
            const float4* p2  = (const float4*)&M2x[(t2k + 1) * 64 + c0];
#pragma unroll
            for (int j = 0; j < 4; j++) {
                float4 a = p01[j];
                float4 bb4 = p2[j];
                float vv[4] = {a.x + bb4.x, a.y + bb4.y, a.z + bb4.z, a.w + bb4.w};
#pragma unroll
                for (int r = 0; r < 4; r++) {
                    float xv = vv[r];
                    xv = xv > 0.f ? xv : __expf(xv) - 1.f;
                    tmp[j * 4 + r] = f2bf(xv);
                }
            }
        } else {
#pragma unroll
            for (int j = 0; j < 16; j++) tmp[j] = 0;
        }
        *(short8*)&s1[q * SSTR + c0] = *(short8*)&tmp[0];
        *(short8*)&s1[q * SSTR + c0 + 8] = *(short8*)&tmp[8];
    }
    __syncthreads();

    // conv2 MFMA. M=64 (4 mt), N=128 (8 nt), K=320 (10 kb); wave wv owns nt = {2wv, 2wv+1}
    int wv = t >> 6, lane = t & 63;
    int ln15 = lane & 15, quad = lane >> 4;

    f32x4 acc2[4][2];
#pragma unroll
    for (int mi = 0; mi < 4; mi++)
#pragma unroll
        for (int ni = 0; ni < 2; ni++) acc2[mi][ni] = (f32x4){0.f, 0.f, 0.f, 0.f};
#pragma unroll 2
    for (int kb = 0; kb < 10; kb++) {
        int koff = kb * 32 + quad * 8;
        int kk = koff >> 6, i0 = koff & 63;
        short8 a[4], bb[2];
#pragma unroll
        for (int mi = 0; mi < 4; mi++)
            a[mi] = *(const short8*)&s1[(mi * 16 + ln15 + kk) * SSTR + i0];
#pragma unroll
        for (int ni = 0; ni < 2; ni++)
            bb[ni] = *(const short8*)&Bswz2[((kb * 8 + wv * 2 + ni) * 64 + lane) * 8];
#pragma unroll
        for (int mi = 0; mi < 4; mi++)
#pragma unroll
            for (int ni = 0; ni < 2; ni++)
                acc2[mi][ni] = __builtin_amdgcn_mfma_f32_16x16x32_bf16(a[mi], bb[ni], acc2[mi][ni], 0, 0, 0);
    }

    // epilogue: masked raw max, plain store per (b,tile,col) — reduced in k_tail
#pragma unroll
    for (int ni = 0; ni < 2; ni++) {
        int col = (wv * 2 + ni) * 16 + ln15;
        float mx = -1e30f;
#pragma unroll
        for (int mi = 0; mi < 4; mi++) {
#pragma unroll
            for (int r = 0; r < 4; r++) {
                int p = mi * 16 + quad * 4 + r;
                if (p < TL && t0 + p < LL) mx = fmaxf(mx, acc2[mi][ni][r]);
            }
        }
        mx = fmaxf(mx, __shfl_xor(mx, 16, 64));
        mx = fmaxf(mx, __shfl_xor(mx, 32, 64));
        if (quad == 0) pmaxp[(b * NTILE + tile) * 128 + col] = mx;
    }
}

// ---------------- D3: merged CSR scan (96 peer blocks, spin barrier; R6-proven) ----------------
__global__ void k_scan(const int* deg, int* rowptr, int* part, int* ctr) {
    __shared__ int s[256];
    __shared__ int sp[96];
    int b = blockIdx.x, t = threadIdx.x, i = b * 256 + t;
    int v = deg[i];
    s[t] = v;
    __syncthreads();
    for (int o = 1; o < 256; o <<= 1) {
        int x2 = (t >= o) ? s[t - o] : 0;
        __syncthreads();
        s[t] += x2;
        __syncthreads();
    }
    int excl = s[t] - v;
    if (t == 255) {
        part[b] = s[t];
        __threadfence();
        atomicAdd(ctr, 1);
    }
    if (t == 0) {
        while (__hip_atomic_load(ctr, __ATOMIC_ACQUIRE, __HIP_MEMORY_SCOPE_AGENT) < 96) {}
    }
    __syncthreads();
    if (t < 96) sp[t] = __hip_atomic_load(&part[t], __ATOMIC_RELAXED, __HIP_MEMORY_SCOPE_AGENT);
    __syncthreads();
    int pref = 0;
    for (int i2 = 0; i2 < b; i2++) pref += sp[i2];
    rowptr[i] = excl + pref;
    if (i == 0) rowptr[NN] = ETOT;
}

// ---------------- D4: scatter ----------------
__global__ void k_scatter(const int* ei, const int* rowptr, int* cursor, int* colidx) {
    int e = blockIdx.x * 256 + threadIdx.x;
    if (e >= ETOT) return;
    int s, d;
    if (e < NE) { s = ei[e]; d = ei[NE + e]; }
    else { s = d = e - NE; }
    int pos = atomicAdd(&cursor[d], 1);
    colidx[rowptr[d] + pos] = s;
}

// ---------------- GAT layer 1: x-space aggregation + fused W1 (packed 64B node records) ----------------
__global__ void k_agg2x(const int* rowptr, const int* colidx, const float* rec,
                        const float* W1, const float* b1, const float* wvec,
                        unsigned int* g1b, float* as2, float* ad2) {
    __shared__ float sW[640];
    __shared__ float sb1[128];
    __shared__ float swa[256];
    int t = threadIdx.x;
    for (int i = t; i < 640; i += 256) sW[i] = W1[i];
    if (t < 128) { sb1[t] = b1[t]; swa[t] = wvec[32 + t]; swa[128 + t] = wvec[160 + t]; }
    __syncthreads();

    int d = blockIdx.x * 16 + (t >> 4);   // grid = NN/16
    int g = t & 15;
    int hd = (g < 5) ? 0 : 1;
    int f = (g < 5) ? g : g - 5;
    float adv = rec[d * 16 + 7 + hd];
    int p0 = rowptr[d], p1 = rowptr[d + 1];
    float den = 0.f, acc = 0.f;
    if (g < 10) {
        for (int pc = p0; pc < p1; pc += 4) {
            int sarr[4]; float ev[4], xv[4];
#pragma unroll
            for (int i = 0; i < 4; i++) {
                int pp = pc + i;
                sarr[i] = colidx[pp < p1 ? pp : p1 - 1];
            }
#pragma unroll
            for (int i = 0; i < 4; i++) {
                ev[i] = rec[sarr[i] * 16 + 5 + hd];
                xv[i] = rec[sarr[i] * 16 + f];
            }
#pragma unroll
            for (int i = 0; i < 4; i++) {
                if (pc + i < p1) {
                    float e = ev[i] + adv;
                    e = e >= 0.f ? e : 0.2f * e;
                    float w = __expf(e);
                    den += w;
                    acc += w * xv[i];
                }
            }
        }
    }
    float xn = acc / (den + 1e-16f);
    int gb = (t & 63) & ~15;
    int hcol = g >> 3;
    float xs[5];
#pragma unroll
    for (int f2 = 0; f2 < 5; f2++)
        xs[f2] = __shfl(xn, gb + hcol * 5 + f2, 64);
    float ps = 0.f, pd = 0.f;
    float g1v[8];
#pragma unroll
    for (int k = 0; k < 8; k++) {
        int col = g * 8 + k;
        float v = sb1[col];
#pragma unroll
        for (int f2 = 0; f2 < 5; f2++) v += xs[f2] * sW[f2 * 128 + col];
        v = v > 0.f ? v : __expf(v) - 1.f;
        g1v[k] = v;
        ps += v * swa[col];
        pd += v * swa[128 + col];
    }
    uint4 pk;
    pk.x = ((unsigned)(unsigned short)f2bf(g1v[1]) << 16) | (unsigned)(unsigned short)f2bf(g1v[0]);
    pk.y = ((unsigned)(unsigned short)f2bf(g1v[3]) << 16) | (unsigned)(unsigned short)f2bf(g1v[2]);
    pk.z = ((unsigned)(unsigned short)f2bf(g1v[5]) << 16) | (unsigned)(unsigned short)f2bf(g1v[4]);
    pk.w = ((unsigned)(unsigned short)f2bf(g1v[7]) << 16) | (unsigned)(unsigned short)f2bf(g1v[6]);
    *(uint4*)&g1b[d * 64 + g * 4] = pk;
#pragma unroll
    for (int msk = 1; msk < 16; msk <<= 1) {
        ps += __shfl_xor(ps, msk, 64);
        pd += __shfl_xor(pd, msk, 64);
    }
    if (g == 0) { as2[d] = ps; ad2[d] = pd; }
}

// ---------------- GAT layer 2 aggregation in g1-space; writes split-bf16 hi/lo directly ----------------
__global__ void k_agg1y(const int* rowptr, const int* colidx, const unsigned int* hb,
                        const float* as_, const float* ad_,
                        unsigned int* yH, unsigned int* yL) {
    int t = threadIdx.x;
    int d = blockIdx.x * 4 + (t >> 6);   // wave per node
    int c = t & 63;
    float adv = ad_[d];
    int p0 = rowptr[d], p1 = rowptr[d + 1];
    float den = 0.f, acc0 = 0.f, acc1 = 0.f;
    for (int pc = p0; pc < p1; pc += 4) {
        int sarr[4]; float ev[4]; unsigned int hv[4];
#pragma unroll
        for (int i = 0; i < 4; i++) {
            int pp = pc + i;
            sarr[i] = colidx[pp < p1 ? pp : p1 - 1];
        }
#pragma unroll
        for (int i = 0; i < 4; i++) {
            ev[i] = as_[sarr[i]];
            hv[i] = hb[sarr[i] * 64 + c];
        }
#pragma unroll
        for (int i = 0; i < 4; i++) {
            if (pc + i < p1) {
                float e = ev[i] + adv;
                e = e >= 0.f ? e : 0.2f * e;
                float w = __expf(e);
                den += w;
                acc0 += w * __uint_as_float(hv[i] << 16);
                acc1 += w * __uint_as_float(hv[i] & 0xFFFF0000u);
            }
        }
    }
    float inv = 1.f / (den + 1e-16f);
    float v0 = acc0 * inv, v1 = acc1 * inv;
    short h0 = f2bf(v0), l0 = f2bf(v0 - bf2f(h0));
    short h1 = f2bf(v1), l1 = f2bf(v1 - bf2f(h1));
    yH[d * 64 + c] = ((unsigned)(unsigned short)h1 << 16) | (unsigned)(unsigned short)h0;
    yL[d * 64 + c] = ((unsigned)(unsigned short)l1 << 16) | (unsigned)(unsigned short)l0;
}

// ---------------- layer-2 matmul + fused mean-pool scatter: sums += elu(y @ W2 + b2) ----------------
#define ASTR 136
__global__ __launch_bounds__(256, 2) void k_g2mm(
    const unsigned int* yH, const unsigned int* yL, const short* Bh, const short* Bl,
    const float* b2, const int* batch, float* sums) {
    __shared__ __align__(16) short Ah[64 * ASTR];
    __shared__ __align__(16) short Al[64 * ASTR];
    __shared__ int sb[64];
    int t = threadIdx.x;
    int m0 = blockIdx.x * 64;
    int wv = t >> 6, lane = t & 63;
    int ln15 = lane & 15, quad = lane >> 4;

    if (t < 64) sb[t] = batch[m0 + t];
    for (int i = t; i < 64 * 16; i += 256) {   // pure uint4 copies (split done in agg1y)
        int row = i >> 4, cu = (i & 15) * 4;
        *(uint4*)&Ah[row * ASTR + cu * 2] = *(const uint4*)&yH[(m0 + row) * 64 + cu];
        *(uint4*)&Al[row * ASTR + cu * 2] = *(const uint4*)&yL[(m0 + row) * 64 + cu];
    }
    __syncthreads();

    f32x4 acc[8];
#pragma unroll
    for (int nt = 0; nt < 8; nt++) acc[nt] = (f32x4){0.f, 0.f, 0.f, 0.f};
    int arow = wv * 16 + ln15;
#pragma unroll
    for (int kb = 0; kb < 4; kb++) {
        int koff = kb * 32 + quad * 8;
        short8 a_hi = *(const short8*)&Ah[arow * ASTR + koff];
        short8 a_lo = *(const short8*)&Al[arow * ASTR + koff];
#pragma unroll
        for (int nt = 0; nt < 8; nt++) {
            short8 bh = *(const short8*)&Bh[((kb * 8 + nt) * 64 + lane) * 8];
            short8 bl = *(const short8*)&Bl[((kb * 8 + nt) * 64 + lane) * 8];
            acc[nt] = __builtin_amdgcn_mfma_f32_16x16x32_bf16(a_hi, bh, acc[nt], 0, 0, 0);
            acc[nt] = __builtin_amdgcn_mfma_f32_16x16x32_bf16(a_hi, bl, acc[nt], 0, 0, 0);
            acc[nt] = __builtin_amdgcn_mfma_f32_16x16x32_bf16(a_lo, bh, acc[nt], 0, 0, 0);
        }
    }
    // epilogue: bias+elu, then segmented (sorted-batch) atomic accumulate into sums
    int rbase = wv * 16 + quad * 4;
#pragma unroll
    for (int nt = 0; nt < 8; nt++) {
        int col = nt * 16 + ln15;
        float bias = b2[col];
        float run = 0.f;
        int cg = sb[rbase];
#pragma unroll
        for (int r = 0; r < 4; r++) {
            float v = acc[nt][r] + bias;
            v = v > 0.f ? v : __expf(v) - 1.f;
            int g = sb[rbase + r];
            if (g != cg) {
                atomicAdd(&sums[cg * 128 + col], run);
                run = 0.f; cg = g;
            }
            run += v;
        }
        atomicAdd(&sums[cg * 128 + col], run);
    }
}

// ---------------- tail: pmax tile-reduce + cnt via binary search + head MLP ----------------
__global__ __launch_bounds__(512) void k_tail(
    const float* pmaxp, const float* bk2, const float* Wp, const float* bp,
    const float* sums, const int* batch, const float* Wd, const float* bd,
    const float* Wf1, const float* bf1, const float* Wf2, const float* bf2,
    const float* Wo, const float* bo, float* out) {
    __shared__ float spm[128];
    __shared__ float in2[512];
    __shared__ float part1[512];
    __shared__ float hh[128];
    __shared__ float part2[512];
    __shared__ float h2s[64];
    __shared__ int sLo, sHi;
    int g = blockIdx.x, t = threadIdx.x;

    if (t < 128) {   // reduce 17 tiles -> bias+elu once (elu monotonic)
        float m = -1e30f;
#pragma unroll
        for (int tt = 0; tt < NTILE; tt++)
            m = fmaxf(m, pmaxp[(g * NTILE + tt) * 128 + t]);
        float v = m + bk2[t];
        spm[t] = v > 0.f ? v : __expf(v) - 1.f;
    } else if (t == 128 || t == 129) {
        // cnt[g] = lower_bound(batch, g+1) - lower_bound(batch, g)  (batch sorted)
        int target = g + (t - 128);
        int lo = 0, hi = NN;
        while (lo < hi) {
            int mid = (lo + hi) >> 1;
            if (batch[mid] < target) lo = mid + 1; else hi = mid;
        }
        if (t == 128) sLo = lo; else sHi = lo;
    }
    __syncthreads();

    if (t < 256) {
        float pacc = bp[t];
#pragma unroll 8
        for (int i = 0; i < 128; i++) pacc += spm[i] * Wp[i * 256 + t];
        in2[256 + t] = pacc > 0.f ? pacc : 0.f;
    } else {
        int o = t - 256;
        float c = (float)(sHi - sLo); c = c < 1.f ? 1.f : c;
        float inv = 1.f / c;
        float dacc = bd[o];
#pragma unroll 8
        for (int i = 0; i < 128; i++) dacc += sums[g * 128 + i] * inv * Wd[i * 256 + o];
        in2[o] = dacc > 0.f ? dacc : 0.f;
    }
    __syncthreads();

    {
        int o = t >> 2, ks = t & 3;
        float p = 0.f;
        int c0 = ks * 128;
#pragma unroll 8
        for (int cc = c0; cc < c0 + 128; cc++) p += in2[cc] * Wf1[cc * 128 + o];
        part1[t] = p;
    }
    __syncthreads();
    if (t < 128) {
        float a = bf1[t] + part1[t * 4] + part1[t * 4 + 1] + part1[t * 4 + 2] + part1[t * 4 + 3];
        hh[t] = a > 0.f ? a : 0.f;
    }
    __syncthreads();

    {
        int o = t >> 3, ks = t & 7;
        float p = 0.f;
        int c0 = ks * 16;
#pragma unroll
        for (int cc = c0; cc < c0 + 16; cc++) p += hh[cc] * Wf2[cc * 64 + o];
        part2[t] = p;
    }
    __syncthreads();
    if (t < 64) {
        float a = bf2[t];
#pragma unroll
        for (int k = 0; k < 8; k++) a += part2[t * 8 + k];
        h2s[t] = a > 0.f ? a : 0.f;
    }
    __syncthreads();

    if (t < 64) {
        float p = h2s[t] * Wo[t];
#pragma unroll
        for (int off = 32; off > 0; off >>= 1) p += __shfl_down(p, off, 64);
        if (t == 0) out[g] = p + bo[0];
    }
}

extern "C" void kernel_launch(void* const* d_in, const int* in_sizes, int n_in,
                              void* d_out, int out_size, void* d_ws, size_t ws_size,
                              hipStream_t stream) {
    (void)in_sizes; (void)n_in; (void)out_size; (void)ws_size;
    const float* x   = (const float*)d_in[0];
    const int* ei    = (const int*)d_in[1];
    const int* batch = (const int*)d_in[2];
    const int* seq   = (const int*)d_in[3];
    const float* W1  = (const float*)d_in[4];
    const float* a_s1 = (const float*)d_in[5];
    const float* a_d1 = (const float*)d_in[6];
    const float* b1  = (const float*)d_in[7];
    const float* W2  = (const float*)d_in[8];
    const float* a_s2 = (const float*)d_in[9];
    const float* a_d2 = (const float*)d_in[10];
    const float* b2  = (const float*)d_in[11];
    const float* Wd  = (const float*)d_in[12];
    const float* bd  = (const float*)d_in[13];
    const float* Pe  = (const float*)d_in[14];
    const float* K1  = (const float*)d_in[15];
    const float* bk1 = (const float*)d_in[16];
    const float* K2  = (const float*)d_in[17];
    const float* bk2 = (const float*)d_in[18];
    const float* Wp  = (const float*)d_in[19];
    const float* bp  = (const float*)d_in[20];
    const float* Wf1 = (const float*)d_in[21];
    const float* bf1 = (const float*)d_in[22];
    const float* Wf2 = (const float*)d_in[23];
    const float* bf2 = (const float*)d_in[24];
    const float* Wo  = (const float*)d_in[25];
    const float* bo  = (const float*)d_in[26];
    float* out = (float*)d_out;

    float* w = (float*)d_ws;
    float* g1bf = w; w += NN * 64;    // packed-bf16 uint[NN*64]
    float* yHf  = w; w += NN * 64;    // split-bf16 hi, uint[NN*64]
    float* yLf  = w; w += NN * 64;    // split-bf16 lo, uint[NN*64]
    float* as2  = w; w += NN;
    float* ad2  = w; w += NN;
    float* sums = w; w += NG * 128;
    float* pmaxp = w; w += NB * NTILE * 128;   // per-tile raw max
    float* rec  = w; w += NN * 16;             // packed {x[5], as1[2], ad1[2]} per node
    float* wvec = w; w += 512;
    short* Bswz2 = (short*)w; w += 320 * 128 / 2;
    short* Bh2  = (short*)w; w += 128 * 128 / 2;
    short* Bl2  = (short*)w; w += 128 * 128 / 2;
    float* M01  = w; w += 506 * 64;
    float* M2x  = w; w += 23 * 64;
    int* deg    = (int*)w; w += NN;
    int* cursor = (int*)w; w += NN;
    int* part   = (int*)w; w += 128;
    int* ctr    = (int*)w; w += 8;
    int* rowptr = (int*)w; w += NN + 8;
    int* colidx = (int*)w; w += ETOT;

    unsigned int* g1b = (unsigned int*)g1bf;
    unsigned int* yH  = (unsigned int*)yHf;
    unsigned int* yL  = (unsigned int*)yLf;

    // D1: init + weight prep
    hipLaunchKernelGGL(k_init_prep, dim3(256 + 160), dim3(256), 0, stream,
                       deg, cursor, sums, ctr,
                       K1, K2, W2, Pe, W1, a_s1, a_d1, a_s2, a_d2, bk1,
                       Bswz2, Bh2, Bl2, M01, M2x, wvec);

    // D2: protein + CSR count + as1/rec
    hipLaunchKernelGGL(k_prot_cnt_as1, dim3(PROT_BLKS + CNT_BLKS + AS1_BLKS), dim3(256), 0, stream,
                       seq, M01, M2x, Bswz2, pmaxp,
                       ei, deg, x, wvec, rec);

    // D3: merged CSR scan (96 peers)
    hipLaunchKernelGGL(k_scan, dim3(NN / 256), dim3(256), 0, stream, deg, rowptr, part, ctr);

    // D4: scatter
    hipLaunchKernelGGL(k_scatter, dim3(ETOT / 256), dim3(256), 0, stream, ei, rowptr, cursor, colidx);

    // D5: GAT layer 1 aggregation (rec-space) + fused W1
    hipLaunchKernelGGL(k_agg2x, dim3(NN / 16), dim3(256), 0, stream,
                       rowptr, colidx, rec, W1, b1, wvec, g1b, as2, ad2);

    // D6: GAT layer 2 aggregation (split-bf16 output)
    hipLaunchKernelGGL(k_agg1y, dim3(NN / 4), dim3(256), 0, stream,
                       rowptr, colidx, g1b, as2, ad2, yH, yL);

    // D7: W2 matmul + fused mean-pool scatter
    hipLaunchKernelGGL(k_g2mm, dim3(NN / 64), dim3(256), 0, stream,
                       yH, yL, Bh2, Bl2, b2, batch, sums);

    // D8: tail (pmax tile-reduce + binary-search cnt)
    hipLaunchKernelGGL(k_tail, dim3(NG), dim3(512), 0, stream,
                       pmaxp, bk2, Wp, bp, sums, batch, Wd, bd, Wf1, bf1, Wf2, bf2, Wo, bo, out);
}